// Round 17
// baseline (110.733 us; speedup 1.0000x reference)
//
#include <hip/hip_runtime.h>
#include <hip/hip_bf16.h>
#include <cstdint>
#include <cstddef>

#define B_SZ   2
#define T_CTX  2048
#define DIM_C  1024
#define NHEAD  16
#define HD     64
#define NBH    (B_SZ*NHEAD)

typedef __attribute__((ext_vector_type(8))) short short8;
typedef __attribute__((ext_vector_type(4))) float f32x4;
typedef __attribute__((ext_vector_type(16))) float f32x16;

union BV8 { short8 s; __hip_bfloat16 h[8]; unsigned short u[8]; };
union U32x4 { uint32_t u[4]; short8 s8; };

#define GLD16(gp, lp) \
  __builtin_amdgcn_global_load_lds((const __attribute__((address_space(1))) void*)(gp), \
                                   (__attribute__((address_space(3))) void*)(lp), 16, 0, 0)

// pack two f32 -> bf16 pair (lo = first arg), pure IR (hazard-safe feed into MFMA)
__device__ inline uint32_t pkbf(float a, float b) {
  union { __hip_bfloat16 h; unsigned short u; } ua, ub;
  ua.h = __float2bfloat16(a);
  ub.h = __float2bfloat16(b);
  return ((uint32_t)ub.u << 16) | (uint32_t)ua.u;
}

// ---------------- fp32 -> bf16 convert, all three inputs in one launch ----------------
__global__ __launch_bounds__(256) void cvt_all(const float* __restrict__ x,
                                               const float* __restrict__ wq,
                                               const float* __restrict__ wo,
                                               __hip_bfloat16* __restrict__ xb,
                                               __hip_bfloat16* __restrict__ wqb,
                                               __hip_bfloat16* __restrict__ wob) {
  int i = blockIdx.x * 256 + threadIdx.x;
  const float* src;
  __hip_bfloat16* dst;
  int off;
  if (i < 1048576) { src = x; dst = xb; off = i; }
  else if (i < 1835008) { src = wq; dst = wqb; off = i - 1048576; }
  else { src = wo; dst = wob; off = i - 1835008; }
  float4 v = reinterpret_cast<const float4*>(src)[off];
  BV8 o;
  o.h[0] = __float2bfloat16(v.x);
  o.h[1] = __float2bfloat16(v.y);
  o.h[2] = __float2bfloat16(v.z);
  o.h[3] = __float2bfloat16(v.w);
  ushort4 st = { o.u[0], o.u[1], o.u[2], o.u[3] };
  reinterpret_cast<ushort4*>(dst)[off] = st;
}

// ---------------- bf16 GEMM, C = A[M,K] * Bt[N,K]^T ----------------
// BK=32, 64B LDS rows (2-way bank alias = free), DOUBLE-BUFFERED staging.
// BN template param: 128 (gemm1: 32KB LDS -> 3 blocks/CU, grid fully resident,
// zero tail) or 64 (gemm2: 24KB LDS, 512 blocks -> 2 blocks/CU, 8 waves/CU).
// T1 XCD chunking.
template <typename OutT, int BN>
__global__ __launch_bounds__(256) void gemm_bt(const __hip_bfloat16* __restrict__ A,
                                               const __hip_bfloat16* __restrict__ Bt,
                                               OutT* __restrict__ C,
                                               int M, int N, int K) {
  constexpr int NB = BN / 32;              // n-frags per wave (4 or 2)
  constexpr int ABYT = 128 * 64;           // 8KB per buffer
  constexpr int BBYT = BN * 64;            // 8KB or 4KB per buffer
  __shared__ __align__(16) char smem[2 * (ABYT + BBYT)];
  const int tid = threadIdx.x;
  const int w = tid >> 6, l = tid & 63;
  const int l15 = l & 15, l4 = l >> 4;
  const int wr = w >> 1, wc = w & 1;
  // T1: bijective XCD chunking (requires nwg % 8 == 0)
  const int gx = (int)gridDim.x;
  const int nwg = gx * (int)gridDim.y;
  int lin = (int)blockIdx.y * gx + (int)blockIdx.x;
  lin = (lin & 7) * (nwg >> 3) + (lin >> 3);
  const long bm = (long)(lin / gx) * 128;
  const long bn = (long)(lin % gx) * BN;

  f32x4 acc[4][NB] = {};

  const int srow = tid >> 2;            // 0..63 (row within 64-row staging group)
  const int scol = (tid & 3) * 16;      // byte col within 64B row
  const char* Ab  = (const char*)A;
  const char* Btb = (const char*)Bt;

#define GSTAGE(kt_, buf_)                                                        \
  {                                                                              \
    char* base_ = smem + (buf_) * (ABYT + BBYT);                                 \
    _Pragma("unroll")                                                            \
    for (int it = 0; it < 2; ++it) {                                             \
      long arow = bm + it * 64 + srow;                                           \
      GLD16(Ab + (arow * K + (kt_)) * 2 + scol, base_ + it * 4096 + w * 1024);   \
    }                                                                            \
    _Pragma("unroll")                                                            \
    for (int it = 0; it < BN / 64; ++it) {                                       \
      long brow = bn + it * 64 + srow;                                           \
      GLD16(Btb + (brow * K + (kt_)) * 2 + scol,                                 \
            base_ + ABYT + it * 4096 + w * 1024);                                \
    }                                                                            \
  }

  GSTAGE(0, 0)

  int cur = 0;
  for (int kt = 0; kt < K; kt += 32) {
    __syncthreads();  // buf[cur] staged; prior reads of buf^1 done
    if (kt + 32 < K) GSTAGE(kt + 32, cur ^ 1)
    const char* Ac = smem + cur * (ABYT + BBYT);
    const char* Bc = Ac + ABYT;
    short8 aF[4], bF[NB];
#pragma unroll
    for (int m = 0; m < 4; ++m)
      aF[m] = *(const short8*)(Ac + (wr * 64 + m * 16 + l15) * 64 + l4 * 16);
#pragma unroll
    for (int n = 0; n < NB; ++n)
      bF[n] = *(const short8*)(Bc + (wc * (BN / 2) + n * 16 + l15) * 64 + l4 * 16);
#pragma unroll
    for (int m = 0; m < 4; ++m)
#pragma unroll
      for (int n = 0; n < NB; ++n)
        acc[m][n] = __builtin_amdgcn_mfma_f32_16x16x32_bf16(aF[m], bF[n], acc[m][n], 0, 0, 0);
    cur ^= 1;
  }
#undef GSTAGE

#pragma unroll
  for (int m = 0; m < 4; ++m)
#pragma unroll
    for (int n = 0; n < NB; ++n)
#pragma unroll
      for (int r = 0; r < 4; ++r) {
        long row = bm + wr * 64 + m * 16 + l4 * 4 + r;
        long col = bn + wc * (BN / 2) + n * 16 + l15;
        float v = acc[m][n][r];
        if constexpr (sizeof(OutT) == 2) {
          C[row * N + col] = __float2bfloat16(v);
        } else {
          C[row * N + col] = v;
        }
      }
}

// ---------------- RoPE + repack (known-good) ----------------
// Q scale folds softmax 1/8 AND log2(e) so attention softmax can use exp2 natively.
__global__ __launch_bounds__(256) void rope_pack(const __hip_bfloat16* __restrict__ qkv,
                                                 __hip_bfloat16* __restrict__ Qb,
                                                 __hip_bfloat16* __restrict__ Kb,
                                                 __hip_bfloat16* __restrict__ VTb) {
  __shared__ __hip_bfloat16 vt[64][72];
  const int bh = blockIdx.x;
  const int b = bh >> 4, h = bh & 15;
  const int t0 = blockIdx.y * 64;
  const int tid = threadIdx.x;
  const float QSCL = 0.125f * 1.4426950408889634f;

#pragma unroll
  for (int rep = 0; rep < 2; ++rep) {
    int idx = rep * 256 + tid;
    int tt = idx >> 3;
    int d0 = (idx & 7) * 8;
    int t = t0 + tt;
    size_t src = ((size_t)(b * T_CTX + t)) * 3072 + h * 64 + d0;
    BV8 qv, kv, vv, qo, ko;
    qv.s = *(const short8*)(qkv + src);
    kv.s = *(const short8*)(qkv + src + 1024);
    vv.s = *(const short8*)(qkv + src + 2048);
#pragma unroll
    for (int p = 0; p < 4; ++p) {
      int i = (d0 >> 1) + p;
      float inv = exp2f(-13.287712379549449f * ((float)(2 * i) * (1.0f / 64.0f)));
      float ang = (float)t * inv;
      float sn, cn;
      sincosf(ang, &sn, &cn);
      float q1 = __bfloat162float(qv.h[2 * p]);
      float q2 = __bfloat162float(qv.h[2 * p + 1]);
      float k1 = __bfloat162float(kv.h[2 * p]);
      float k2 = __bfloat162float(kv.h[2 * p + 1]);
      qo.h[2 * p]     = __float2bfloat16((q1 * cn - q2 * sn) * QSCL);
      qo.h[2 * p + 1] = __float2bfloat16((q1 * sn + q2 * cn) * QSCL);
      ko.h[2 * p]     = __float2bfloat16(k1 * cn - k2 * sn);
      ko.h[2 * p + 1] = __float2bfloat16(k1 * sn + k2 * cn);
    }
    size_t dst = ((size_t)bh * T_CTX + t) * 64 + d0;
    *(short8*)(Qb + dst) = qo.s;
    *(short8*)(Kb + dst) = ko.s;
#pragma unroll
    for (int j = 0; j < 8; ++j) vt[d0 + j][tt] = vv.h[j];
  }
  __syncthreads();
#pragma unroll
  for (int rep = 0; rep < 2; ++rep) {
    int idx = rep * 256 + tid;
    int d = idx >> 3;
    int toff = (idx & 7) * 8;
    BV8 o;
#pragma unroll
    for (int j = 0; j < 8; ++j) o.h[j] = vt[d][toff + j];
    *(short8*)(VTb + ((size_t)bh * 64 + d) * T_CTX + t0 + toff) = o.s;
  }
}

// ---------------- flash attention (causal), 32x32 MFMA, paired-tile barriers ----------------
// (round-12 known-good: 4 waves = qsub x kh, 64-row balanced slab pairs, k-split,
// fixed-base exp2 softmax, end-of-kernel merge, two KV tiles per barrier)
__global__ __launch_bounds__(256) void flash_attn(const __hip_bfloat16* __restrict__ Qb,
                                                  const __hip_bfloat16* __restrict__ Kb,
                                                  const __hip_bfloat16* __restrict__ VTb,
                                                  __hip_bfloat16* __restrict__ Y) {
  __shared__ __align__(16) char smem[65536];
  const int bh = blockIdx.x;
  const int b = bh >> 4, h = bh & 15;
  const int y = blockIdx.y;
  const int jA = 31 - y;
  const int jB = y;
  const int tid = threadIdx.x;
  const int w = tid >> 6, l = tid & 63;
  const int qsub = w >> 1, kh = w & 1;
  const int l31 = l & 31, hh = l >> 5;
  const int sw7 = (l31 & 7) << 4;
  const int rowb = tid >> 3;
  const int colS = (tid & 7) * 16;

#define STAGE1(gg)                                                                     \
  {                                                                                    \
    const int tt_ = ((gg) <= jA) ? (gg) : (gg) - jA - 1;                               \
    const int kv0_ = tt_ << 6;                                                         \
    char* base_ = smem + (((gg) >> 1) & 1) * 32768 + ((gg) & 1) * 16384;               \
    _Pragma("unroll")                                                                  \
    for (int rnd = 0; rnd < 2; ++rnd) {                                                \
      int row = rnd * 32 + rowb;                                                       \
      int sw = colS ^ ((row & 7) << 4);                                                \
      GLD16((const char*)Kb + (((size_t)bh * T_CTX + kv0_ + row) << 7) + sw,           \
            base_ + rnd * 4096 + w * 1024);                                            \
      GLD16((const char*)VTb + ((((size_t)bh * 64 + row) * T_CTX + kv0_) << 1) + sw,   \
            base_ + 8192 + rnd * 4096 + w * 1024);                                     \
    }                                                                                  \
  }

  f32x16 oA0 = {}, oA1 = {}, oB0 = {}, oB1 = {};
  float lrA = 0.0f, lrB = 0.0f;

  STAGE1(0)
  STAGE1(1)

  int rr = 0;
#pragma unroll
  for (int ph = 0; ph < 2; ++ph) {
    const int j = ph ? jB : jA;
    const int qglob = j * 64 + qsub * 32 + l31;
    f32x16& od0 = ph ? oB0 : oA0;
    f32x16& od1 = ph ? oB1 : oA1;
    float& lrw = ph ? lrB : lrA;

    short8 qB[4];
#pragma unroll
    for (int dblk = 0; dblk < 4; ++dblk)
      qB[dblk] = *(const short8*)(Qb + ((size_t)bh * T_CTX + qglob) * 64 + dblk * 16 + hh * 8);

    for (int t = 0; t <= j; ++t, ++rr) {
      if ((rr & 1) == 0) {
        __syncthreads();
        if (rr + 2 <= 32) STAGE1(rr + 2)
        if (rr + 3 <= 32) STAGE1(rr + 3)
      }
      const char* KsB = smem + ((rr >> 1) & 1) * 32768 + (rr & 1) * 16384;
      const char* VsB = KsB + 8192;
      const int kv0 = t << 6;
      const bool lastT = (t == j);

      if (!(lastT && kh > qsub)) {
        short8 kA[4];
#pragma unroll
        for (int dblk = 0; dblk < 4; ++dblk)
          kA[dblk] = *(const short8*)(KsB + (kh * 32 + l31) * 128 + ((dblk * 32 + hh * 16) ^ sw7));
        short8 vA[2][2];
#pragma unroll
        for (int dt = 0; dt < 2; ++dt)
#pragma unroll
          for (int ks = 0; ks < 2; ++ks)
            vA[dt][ks] = *(const short8*)(VsB + (dt * 32 + l31) * 128 +
                                          ((kh * 64 + ks * 32 + hh * 16) ^ sw7));

        f32x16 sT = {};
#pragma unroll
        for (int dblk = 0; dblk < 4; ++dblk) {
          __builtin_amdgcn_s_setprio(1);
          sT = __builtin_amdgcn_mfma_f32_32x32x16_bf16(kA[dblk], qB[dblk], sT, 0, 0, 0);
          __builtin_amdgcn_s_setprio(0);
        }
        if (lastT && kh == qsub) {
          const int kbase = kv0 + kh * 32 + 4 * hh;
#pragma unroll
          for (int r = 0; r < 16; ++r) {
            int kg = kbase + (r & 3) + 8 * (r >> 2);
            sT[r] = (kg > qglob) ? -1e30f : sT[r];
          }
        }
        float s8[8];
#pragma unroll
        for (int i = 0; i < 8; ++i) {
          sT[i]     = __builtin_amdgcn_exp2f(sT[i]);
          sT[i + 8] = __builtin_amdgcn_exp2f(sT[i + 8]);
          s8[i] = sT[i] + sT[i + 8];
        }
        float ps = ((s8[0] + s8[1]) + (s8[2] + s8[3])) + ((s8[4] + s8[5]) + (s8[6] + s8[7]));
        ps += __shfl_xor(ps, 32);
        lrw += ps;
        uint32_t wk[8];
#pragma unroll
        for (int i = 0; i < 8; ++i) wk[i] = pkbf(sT[2 * i], sT[2 * i + 1]);
#pragma unroll
        for (int ks = 0; ks < 2; ++ks) {
          const int base = ks * 4;
          uint32_t own0 = wk[base + 0], own1 = wk[base + 1];
          uint32_t own2 = wk[base + 2], own3 = wk[base + 3];
          uint32_t e0 = (uint32_t)__shfl_xor((int)(hh ? own0 : own2), 32);
          uint32_t e1 = (uint32_t)__shfl_xor((int)(hh ? own1 : own3), 32);
          U32x4 u;
          u.u[0] = hh ? e0 : own0;
          u.u[1] = hh ? e1 : own1;
          u.u[2] = hh ? own2 : e0;
          u.u[3] = hh ? own3 : e1;
          __builtin_amdgcn_s_setprio(1);
          od0 = __builtin_amdgcn_mfma_f32_32x32x16_bf16(vA[0][ks], u.s8, od0, 0, 0, 0);
          od1 = __builtin_amdgcn_mfma_f32_32x32x16_bf16(vA[1][ks], u.s8, od1, 0, 0, 0);
          __builtin_amdgcn_s_setprio(0);
        }
      }
    }
  }

  __syncthreads();
  {
    float* exch = (float*)smem;
    float* lst = exch + 8192;
    const int slotA = (0 * 2 + qsub) * 2 + kh;
    const int slotB = (1 * 2 + qsub) * 2 + kh;
    const f32x16& nA = kh ? oA0 : oA1;
    const f32x16& nB = kh ? oB0 : oB1;
#pragma unroll
    for (int m = 0; m < 4; ++m) {
      int c = ((2 * m + hh) ^ (l31 & 7)) * 4;
      f32x4 va, vb;
#pragma unroll
      for (int i = 0; i < 4; ++i) { va[i] = nA[m * 4 + i]; vb[i] = nB[m * 4 + i]; }
      *(f32x4*)(exch + slotA * 1024 + l31 * 32 + c) = va;
      *(f32x4*)(exch + slotB * 1024 + l31 * 32 + c) = vb;
    }
    if (hh == 0) {
      lst[slotA * 32 + l31] = lrA;
      lst[slotB * 32 + l31] = lrB;
    }
    __syncthreads();
    const int pA = (0 * 2 + qsub) * 2 + (kh ^ 1);
    const int pB = (1 * 2 + qsub) * 2 + (kh ^ 1);
    float ltA = lrA + lst[pA * 32 + l31];
    float ltB = lrB + lst[pB * 32 + l31];
    f32x16& ownA = kh ? oA1 : oA0;
    f32x16& ownB = kh ? oB1 : oB0;
#pragma unroll
    for (int m = 0; m < 4; ++m) {
      int c = ((2 * m + hh) ^ (l31 & 7)) * 4;
      f32x4 aA = *(const f32x4*)(exch + pA * 1024 + l31 * 32 + c);
      f32x4 aB = *(const f32x4*)(exch + pB * 1024 + l31 * 32 + c);
#pragma unroll
      for (int i = 0; i < 4; ++i) { ownA[m * 4 + i] += aA[i]; ownB[m * 4 + i] += aB[i]; }
    }
#pragma unroll
    for (int sl = 0; sl < 2; ++sl) {
      const f32x16& ov = sl ? ownB : ownA;
      float inv = 1.0f / (sl ? ltB : ltA);
      int q0s = (sl ? jB : jA) * 64 + qsub * 32;
      size_t rowoff = ((size_t)(b * T_CTX + q0s + l31)) * DIM_C + h * 64 + kh * 32;
#pragma unroll
      for (int m = 0; m < 4; ++m) {
        union { ushort4 v; unsigned short us[4]; } st;
#pragma unroll
        for (int i = 0; i < 4; ++i) {
          union { __hip_bfloat16 h2; unsigned short u; } cv;
          cv.h2 = __float2bfloat16(ov[m * 4 + i] * inv);
          st.us[i] = cv.u;
        }
        *(ushort4*)(Y + rowoff + 8 * m + 4 * hh) = st.v;
      }
    }
  }
#undef STAGE1
}

// ---------------- launcher ----------------
extern "C" void kernel_launch(void* const* d_in, const int* in_sizes, int n_in,
                              void* d_out, int out_size, void* d_ws, size_t ws_size,
                              hipStream_t stream) {
  const float* x     = (const float*)d_in[0];
  const float* qkv_w = (const float*)d_in[1];
  const float* out_w = (const float*)d_in[2];
  float* out = (float*)d_out;

  char* ws = (char*)d_ws;
  const size_t MB = 1024 * 1024;
  __hip_bfloat16* xb    = (__hip_bfloat16*)(ws + 0 * MB);
  __hip_bfloat16* wqkvb = (__hip_bfloat16*)(ws + 8 * MB);
  __hip_bfloat16* woutb = (__hip_bfloat16*)(ws + 14 * MB);
  __hip_bfloat16* qkvb  = (__hip_bfloat16*)(ws + 16 * MB);
  __hip_bfloat16* Qb    = (__hip_bfloat16*)(ws + 40 * MB);
  __hip_bfloat16* Kb    = (__hip_bfloat16*)(ws + 48 * MB);
  __hip_bfloat16* VTb   = (__hip_bfloat16*)(ws + 56 * MB);
  __hip_bfloat16* yb    = (__hip_bfloat16*)(ws + 64 * MB);

  // single fused convert launch
  cvt_all<<<8192, 256, 0, stream>>>(x, qkv_w, out_w, xb, wqkvb, woutb);

  // qkv = x @ qkv_w^T (BK=32 dbuf, 32KB LDS -> 3 blocks/CU, 768 blocks fully resident)
  gemm_bt<__hip_bfloat16, 128><<<dim3(24, 32), 256, 0, stream>>>(xb, wqkvb, qkvb, 4096, 3072, 1024);

  rope_pack<<<dim3(32, 32), 256, 0, stream>>>(qkvb, Qb, Kb, VTb);

  // 16 slab-pairs (31-y, y of 64-row slabs) x 32 bh = 512 blocks, 4 waves each
  flash_attn<<<dim3(NBH, 16), 256, 0, stream>>>(Qb, Kb, VTb, yb);

  // out = y @ out_w^T (BM=128 x BN=64, 512 blocks -> 2 blocks/CU, fp32 out)
  gemm_bt<float, 64><<<dim3(16, 32), 256, 0, stream>>>(yb, woutb, out, 4096, 1024, 1024);
}

// Round 18
// 104.593 us; speedup vs baseline: 1.0587x; 1.0587x over previous
//
#include <hip/hip_runtime.h>
#include <hip/hip_bf16.h>
#include <cstdint>
#include <cstddef>

#define B_SZ   2
#define T_CTX  2048
#define DIM_C  1024
#define NHEAD  16
#define HD     64
#define NBH    (B_SZ*NHEAD)

typedef __attribute__((ext_vector_type(8))) short short8;
typedef __attribute__((ext_vector_type(4))) float f32x4;
typedef __attribute__((ext_vector_type(16))) float f32x16;

union BV8 { short8 s; __hip_bfloat16 h[8]; unsigned short u[8]; };
union U32x4 { uint32_t u[4]; short8 s8; };

#define GLD16(gp, lp) \
  __builtin_amdgcn_global_load_lds((const __attribute__((address_space(1))) void*)(gp), \
                                   (__attribute__((address_space(3))) void*)(lp), 16, 0, 0)

// pack two f32 -> bf16 pair (lo = first arg), pure IR (hazard-safe feed into MFMA)
__device__ inline uint32_t pkbf(float a, float b) {
  union { __hip_bfloat16 h; unsigned short u; } ua, ub;
  ua.h = __float2bfloat16(a);
  ub.h = __float2bfloat16(b);
  return ((uint32_t)ub.u << 16) | (uint32_t)ua.u;
}

// ---------------- fp32 -> bf16 convert, all three inputs in one launch ----------------
__global__ __launch_bounds__(256) void cvt_all(const float* __restrict__ x,
                                               const float* __restrict__ wq,
                                               const float* __restrict__ wo,
                                               __hip_bfloat16* __restrict__ xb,
                                               __hip_bfloat16* __restrict__ wqb,
                                               __hip_bfloat16* __restrict__ wob) {
  int i = blockIdx.x * 256 + threadIdx.x;
  const float* src;
  __hip_bfloat16* dst;
  int off;
  if (i < 1048576) { src = x; dst = xb; off = i; }
  else if (i < 1835008) { src = wq; dst = wqb; off = i - 1048576; }
  else { src = wo; dst = wob; off = i - 1835008; }
  float4 v = reinterpret_cast<const float4*>(src)[off];
  BV8 o;
  o.h[0] = __float2bfloat16(v.x);
  o.h[1] = __float2bfloat16(v.y);
  o.h[2] = __float2bfloat16(v.z);
  o.h[3] = __float2bfloat16(v.w);
  ushort4 st = { o.u[0], o.u[1], o.u[2], o.u[3] };
  reinterpret_cast<ushort4*>(dst)[off] = st;
}

// ---------------- bf16 GEMM, C = A[M,K] * Bt[N,K]^T ----------------
// BK=64, DOUBLE-BUFFERED staging (round-16 proven). BN = 128 (gemm1) or 64
// (gemm2: 48KB LDS -> grid 512 blocks, 2 resident/CU instead of 1).
// 128B LDS rows via pre-swizzled global source (scol ^ ((row&7)<<4)), linear
// global_load_lds dest, same XOR on ds_read_b128. T1 XCD chunking.
template <typename OutT, int BN>
__global__ __launch_bounds__(256) void gemm_bt(const __hip_bfloat16* __restrict__ A,
                                               const __hip_bfloat16* __restrict__ Bt,
                                               OutT* __restrict__ C,
                                               int M, int N, int K) {
  constexpr int NB = BN / 32;               // n-frags per wave (4 or 2)
  constexpr int ABYT = 128 * 128;           // 16KB per buffer
  constexpr int BBYT = BN * 128;            // 16KB or 8KB per buffer
  __shared__ __align__(16) char smem[2 * (ABYT + BBYT)];
  const int tid = threadIdx.x;
  const int w = tid >> 6, l = tid & 63;
  const int l15 = l & 15, l4 = l >> 4;
  const int wr = w >> 1, wc = w & 1;
  // T1: bijective XCD chunking (requires nwg % 8 == 0)
  const int gx = (int)gridDim.x;
  const int nwg = gx * (int)gridDim.y;
  int lin = (int)blockIdx.y * gx + (int)blockIdx.x;
  lin = (lin & 7) * (nwg >> 3) + (lin >> 3);
  const long bm = (long)(lin / gx) * 128;
  const long bn = (long)(lin % gx) * BN;

  f32x4 acc[4][NB] = {};

  const int srow = tid >> 3;            // 0..31 (row within 32-row staging group)
  const int scol = (tid & 7) * 16;      // byte col within 128B row
  const int ssw  = scol ^ ((srow & 7) << 4);  // pre-swizzled source column
  const char* Ab  = (const char*)A;
  const char* Btb = (const char*)Bt;

#define GSTAGE(kt_, buf_)                                                                \
  {                                                                                      \
    char* base_ = smem + (buf_) * (ABYT + BBYT);                                         \
    _Pragma("unroll")                                                                    \
    for (int it = 0; it < 4; ++it) {                                                     \
      long arow = bm + it * 32 + srow;                                                   \
      GLD16(Ab + (arow * K + (kt_)) * 2 + ssw, base_ + it * 4096 + w * 1024);            \
    }                                                                                    \
    _Pragma("unroll")                                                                    \
    for (int it = 0; it < BN / 32; ++it) {                                               \
      long brow = bn + it * 32 + srow;                                                   \
      GLD16(Btb + (brow * K + (kt_)) * 2 + ssw, base_ + ABYT + it * 4096 + w * 1024);    \
    }                                                                                    \
  }

  GSTAGE(0, 0)

  int cur = 0;
  for (int kt = 0; kt < K; kt += 64) {
    __syncthreads();  // buf[cur] staged (vmcnt drained); prior reads of buf^1 done
    if (kt + 64 < K) GSTAGE(kt + 64, cur ^ 1)
    const char* Ac = smem + cur * (ABYT + BBYT);
    const char* Bc = Ac + ABYT;
#pragma unroll
    for (int ksub = 0; ksub < 2; ++ksub) {
      short8 aF[4], bF[NB];
#pragma unroll
      for (int m = 0; m < 4; ++m) {
        int R = wr * 64 + m * 16 + l15;
        aF[m] = *(const short8*)(Ac + R * 128 + ((ksub * 64 + l4 * 16) ^ ((R & 7) << 4)));
      }
#pragma unroll
      for (int n = 0; n < NB; ++n) {
        int R = wc * (BN / 2) + n * 16 + l15;
        bF[n] = *(const short8*)(Bc + R * 128 + ((ksub * 64 + l4 * 16) ^ ((R & 7) << 4)));
      }
#pragma unroll
      for (int m = 0; m < 4; ++m)
#pragma unroll
        for (int n = 0; n < NB; ++n)
          acc[m][n] = __builtin_amdgcn_mfma_f32_16x16x32_bf16(aF[m], bF[n], acc[m][n], 0, 0, 0);
    }
    cur ^= 1;
  }
#undef GSTAGE

#pragma unroll
  for (int m = 0; m < 4; ++m)
#pragma unroll
    for (int n = 0; n < NB; ++n)
#pragma unroll
      for (int r = 0; r < 4; ++r) {
        long row = bm + wr * 64 + m * 16 + l4 * 4 + r;
        long col = bn + wc * (BN / 2) + n * 16 + l15;
        float v = acc[m][n][r];
        if constexpr (sizeof(OutT) == 2) {
          C[row * N + col] = __float2bfloat16(v);
        } else {
          C[row * N + col] = v;
        }
      }
}

// ---------------- RoPE + repack (known-good) ----------------
// Q scale folds softmax 1/8 AND log2(e) so attention softmax can use exp2 natively.
__global__ __launch_bounds__(256) void rope_pack(const __hip_bfloat16* __restrict__ qkv,
                                                 __hip_bfloat16* __restrict__ Qb,
                                                 __hip_bfloat16* __restrict__ Kb,
                                                 __hip_bfloat16* __restrict__ VTb) {
  __shared__ __hip_bfloat16 vt[64][72];
  const int bh = blockIdx.x;
  const int b = bh >> 4, h = bh & 15;
  const int t0 = blockIdx.y * 64;
  const int tid = threadIdx.x;
  const float QSCL = 0.125f * 1.4426950408889634f;

#pragma unroll
  for (int rep = 0; rep < 2; ++rep) {
    int idx = rep * 256 + tid;
    int tt = idx >> 3;
    int d0 = (idx & 7) * 8;
    int t = t0 + tt;
    size_t src = ((size_t)(b * T_CTX + t)) * 3072 + h * 64 + d0;
    BV8 qv, kv, vv, qo, ko;
    qv.s = *(const short8*)(qkv + src);
    kv.s = *(const short8*)(qkv + src + 1024);
    vv.s = *(const short8*)(qkv + src + 2048);
#pragma unroll
    for (int p = 0; p < 4; ++p) {
      int i = (d0 >> 1) + p;
      float inv = exp2f(-13.287712379549449f * ((float)(2 * i) * (1.0f / 64.0f)));
      float ang = (float)t * inv;
      float sn, cn;
      sincosf(ang, &sn, &cn);
      float q1 = __bfloat162float(qv.h[2 * p]);
      float q2 = __bfloat162float(qv.h[2 * p + 1]);
      float k1 = __bfloat162float(kv.h[2 * p]);
      float k2 = __bfloat162float(kv.h[2 * p + 1]);
      qo.h[2 * p]     = __float2bfloat16((q1 * cn - q2 * sn) * QSCL);
      qo.h[2 * p + 1] = __float2bfloat16((q1 * sn + q2 * cn) * QSCL);
      ko.h[2 * p]     = __float2bfloat16(k1 * cn - k2 * sn);
      ko.h[2 * p + 1] = __float2bfloat16(k1 * sn + k2 * cn);
    }
    size_t dst = ((size_t)bh * T_CTX + t) * 64 + d0;
    *(short8*)(Qb + dst) = qo.s;
    *(short8*)(Kb + dst) = ko.s;
#pragma unroll
    for (int j = 0; j < 8; ++j) vt[d0 + j][tt] = vv.h[j];
  }
  __syncthreads();
#pragma unroll
  for (int rep = 0; rep < 2; ++rep) {
    int idx = rep * 256 + tid;
    int d = idx >> 3;
    int toff = (idx & 7) * 8;
    BV8 o;
#pragma unroll
    for (int j = 0; j < 8; ++j) o.h[j] = vt[d][toff + j];
    *(short8*)(VTb + ((size_t)bh * 64 + d) * T_CTX + t0 + toff) = o.s;
  }
}

// ---------------- flash attention (causal), 32x32 MFMA, paired-tile barriers ----------------
// (round-12 known-good: 4 waves = qsub x kh, 64-row balanced slab pairs, k-split,
// fixed-base exp2 softmax, end-of-kernel merge, two KV tiles per barrier)
__global__ __launch_bounds__(256) void flash_attn(const __hip_bfloat16* __restrict__ Qb,
                                                  const __hip_bfloat16* __restrict__ Kb,
                                                  const __hip_bfloat16* __restrict__ VTb,
                                                  __hip_bfloat16* __restrict__ Y) {
  __shared__ __align__(16) char smem[65536];
  const int bh = blockIdx.x;
  const int b = bh >> 4, h = bh & 15;
  const int y = blockIdx.y;
  const int jA = 31 - y;
  const int jB = y;
  const int tid = threadIdx.x;
  const int w = tid >> 6, l = tid & 63;
  const int qsub = w >> 1, kh = w & 1;
  const int l31 = l & 31, hh = l >> 5;
  const int sw7 = (l31 & 7) << 4;
  const int rowb = tid >> 3;
  const int colS = (tid & 7) * 16;

#define STAGE1(gg)                                                                     \
  {                                                                                    \
    const int tt_ = ((gg) <= jA) ? (gg) : (gg) - jA - 1;                               \
    const int kv0_ = tt_ << 6;                                                         \
    char* base_ = smem + (((gg) >> 1) & 1) * 32768 + ((gg) & 1) * 16384;               \
    _Pragma("unroll")                                                                  \
    for (int rnd = 0; rnd < 2; ++rnd) {                                                \
      int row = rnd * 32 + rowb;                                                       \
      int sw = colS ^ ((row & 7) << 4);                                                \
      GLD16((const char*)Kb + (((size_t)bh * T_CTX + kv0_ + row) << 7) + sw,           \
            base_ + rnd * 4096 + w * 1024);                                            \
      GLD16((const char*)VTb + ((((size_t)bh * 64 + row) * T_CTX + kv0_) << 1) + sw,   \
            base_ + 8192 + rnd * 4096 + w * 1024);                                     \
    }                                                                                  \
  }

  f32x16 oA0 = {}, oA1 = {}, oB0 = {}, oB1 = {};
  float lrA = 0.0f, lrB = 0.0f;

  STAGE1(0)
  STAGE1(1)

  int rr = 0;
#pragma unroll
  for (int ph = 0; ph < 2; ++ph) {
    const int j = ph ? jB : jA;
    const int qglob = j * 64 + qsub * 32 + l31;
    f32x16& od0 = ph ? oB0 : oA0;
    f32x16& od1 = ph ? oB1 : oA1;
    float& lrw = ph ? lrB : lrA;

    short8 qB[4];
#pragma unroll
    for (int dblk = 0; dblk < 4; ++dblk)
      qB[dblk] = *(const short8*)(Qb + ((size_t)bh * T_CTX + qglob) * 64 + dblk * 16 + hh * 8);

    for (int t = 0; t <= j; ++t, ++rr) {
      if ((rr & 1) == 0) {
        __syncthreads();
        if (rr + 2 <= 32) STAGE1(rr + 2)
        if (rr + 3 <= 32) STAGE1(rr + 3)
      }
      const char* KsB = smem + ((rr >> 1) & 1) * 32768 + (rr & 1) * 16384;
      const char* VsB = KsB + 8192;
      const int kv0 = t << 6;
      const bool lastT = (t == j);

      if (!(lastT && kh > qsub)) {
        short8 kA[4];
#pragma unroll
        for (int dblk = 0; dblk < 4; ++dblk)
          kA[dblk] = *(const short8*)(KsB + (kh * 32 + l31) * 128 + ((dblk * 32 + hh * 16) ^ sw7));
        short8 vA[2][2];
#pragma unroll
        for (int dt = 0; dt < 2; ++dt)
#pragma unroll
          for (int ks = 0; ks < 2; ++ks)
            vA[dt][ks] = *(const short8*)(VsB + (dt * 32 + l31) * 128 +
                                          ((kh * 64 + ks * 32 + hh * 16) ^ sw7));

        f32x16 sT = {};
#pragma unroll
        for (int dblk = 0; dblk < 4; ++dblk) {
          __builtin_amdgcn_s_setprio(1);
          sT = __builtin_amdgcn_mfma_f32_32x32x16_bf16(kA[dblk], qB[dblk], sT, 0, 0, 0);
          __builtin_amdgcn_s_setprio(0);
        }
        if (lastT && kh == qsub) {
          const int kbase = kv0 + kh * 32 + 4 * hh;
#pragma unroll
          for (int r = 0; r < 16; ++r) {
            int kg = kbase + (r & 3) + 8 * (r >> 2);
            sT[r] = (kg > qglob) ? -1e30f : sT[r];
          }
        }
        float s8[8];
#pragma unroll
        for (int i = 0; i < 8; ++i) {
          sT[i]     = __builtin_amdgcn_exp2f(sT[i]);
          sT[i + 8] = __builtin_amdgcn_exp2f(sT[i + 8]);
          s8[i] = sT[i] + sT[i + 8];
        }
        float ps = ((s8[0] + s8[1]) + (s8[2] + s8[3])) + ((s8[4] + s8[5]) + (s8[6] + s8[7]));
        ps += __shfl_xor(ps, 32);
        lrw += ps;
        uint32_t wk[8];
#pragma unroll
        for (int i = 0; i < 8; ++i) wk[i] = pkbf(sT[2 * i], sT[2 * i + 1]);
#pragma unroll
        for (int ks = 0; ks < 2; ++ks) {
          const int base = ks * 4;
          uint32_t own0 = wk[base + 0], own1 = wk[base + 1];
          uint32_t own2 = wk[base + 2], own3 = wk[base + 3];
          uint32_t e0 = (uint32_t)__shfl_xor((int)(hh ? own0 : own2), 32);
          uint32_t e1 = (uint32_t)__shfl_xor((int)(hh ? own1 : own3), 32);
          U32x4 u;
          u.u[0] = hh ? e0 : own0;
          u.u[1] = hh ? e1 : own1;
          u.u[2] = hh ? own2 : e0;
          u.u[3] = hh ? own3 : e1;
          __builtin_amdgcn_s_setprio(1);
          od0 = __builtin_amdgcn_mfma_f32_32x32x16_bf16(vA[0][ks], u.s8, od0, 0, 0, 0);
          od1 = __builtin_amdgcn_mfma_f32_32x32x16_bf16(vA[1][ks], u.s8, od1, 0, 0, 0);
          __builtin_amdgcn_s_setprio(0);
        }
      }
    }
  }

  __syncthreads();
  {
    float* exch = (float*)smem;
    float* lst = exch + 8192;
    const int slotA = (0 * 2 + qsub) * 2 + kh;
    const int slotB = (1 * 2 + qsub) * 2 + kh;
    const f32x16& nA = kh ? oA0 : oA1;
    const f32x16& nB = kh ? oB0 : oB1;
#pragma unroll
    for (int m = 0; m < 4; ++m) {
      int c = ((2 * m + hh) ^ (l31 & 7)) * 4;
      f32x4 va, vb;
#pragma unroll
      for (int i = 0; i < 4; ++i) { va[i] = nA[m * 4 + i]; vb[i] = nB[m * 4 + i]; }
      *(f32x4*)(exch + slotA * 1024 + l31 * 32 + c) = va;
      *(f32x4*)(exch + slotB * 1024 + l31 * 32 + c) = vb;
    }
    if (hh == 0) {
      lst[slotA * 32 + l31] = lrA;
      lst[slotB * 32 + l31] = lrB;
    }
    __syncthreads();
    const int pA = (0 * 2 + qsub) * 2 + (kh ^ 1);
    const int pB = (1 * 2 + qsub) * 2 + (kh ^ 1);
    float ltA = lrA + lst[pA * 32 + l31];
    float ltB = lrB + lst[pB * 32 + l31];
    f32x16& ownA = kh ? oA1 : oA0;
    f32x16& ownB = kh ? oB1 : oB0;
#pragma unroll
    for (int m = 0; m < 4; ++m) {
      int c = ((2 * m + hh) ^ (l31 & 7)) * 4;
      f32x4 aA = *(const f32x4*)(exch + pA * 1024 + l31 * 32 + c);
      f32x4 aB = *(const f32x4*)(exch + pB * 1024 + l31 * 32 + c);
#pragma unroll
      for (int i = 0; i < 4; ++i) { ownA[m * 4 + i] += aA[i]; ownB[m * 4 + i] += aB[i]; }
    }
#pragma unroll
    for (int sl = 0; sl < 2; ++sl) {
      const f32x16& ov = sl ? ownB : ownA;
      float inv = 1.0f / (sl ? ltB : ltA);
      int q0s = (sl ? jB : jA) * 64 + qsub * 32;
      size_t rowoff = ((size_t)(b * T_CTX + q0s + l31)) * DIM_C + h * 64 + kh * 32;
#pragma unroll
      for (int m = 0; m < 4; ++m) {
        union { ushort4 v; unsigned short us[4]; } st;
#pragma unroll
        for (int i = 0; i < 4; ++i) {
          union { __hip_bfloat16 h2; unsigned short u; } cv;
          cv.h2 = __float2bfloat16(ov[m * 4 + i] * inv);
          st.us[i] = cv.u;
        }
        *(ushort4*)(Y + rowoff + 8 * m + 4 * hh) = st.v;
      }
    }
  }
#undef STAGE1
}

// ---------------- launcher ----------------
extern "C" void kernel_launch(void* const* d_in, const int* in_sizes, int n_in,
                              void* d_out, int out_size, void* d_ws, size_t ws_size,
                              hipStream_t stream) {
  const float* x     = (const float*)d_in[0];
  const float* qkv_w = (const float*)d_in[1];
  const float* out_w = (const float*)d_in[2];
  float* out = (float*)d_out;

  char* ws = (char*)d_ws;
  const size_t MB = 1024 * 1024;
  __hip_bfloat16* xb    = (__hip_bfloat16*)(ws + 0 * MB);
  __hip_bfloat16* wqkvb = (__hip_bfloat16*)(ws + 8 * MB);
  __hip_bfloat16* woutb = (__hip_bfloat16*)(ws + 14 * MB);
  __hip_bfloat16* qkvb  = (__hip_bfloat16*)(ws + 16 * MB);
  __hip_bfloat16* Qb    = (__hip_bfloat16*)(ws + 40 * MB);
  __hip_bfloat16* Kb    = (__hip_bfloat16*)(ws + 48 * MB);
  __hip_bfloat16* VTb   = (__hip_bfloat16*)(ws + 56 * MB);
  __hip_bfloat16* yb    = (__hip_bfloat16*)(ws + 64 * MB);

  // single fused convert launch
  cvt_all<<<8192, 256, 0, stream>>>(x, qkv_w, out_w, xb, wqkvb, woutb);

  // qkv = x @ qkv_w^T (round-16 proven: BK=64 dbuf, BN=128)
  gemm_bt<__hip_bfloat16, 128><<<dim3(24, 32), 256, 0, stream>>>(xb, wqkvb, qkvb, 4096, 3072, 1024);

  rope_pack<<<dim3(32, 32), 256, 0, stream>>>(qkvb, Qb, Kb, VTb);

  // 16 slab-pairs (31-y, y of 64-row slabs) x 32 bh = 512 blocks, 4 waves each
  flash_attn<<<dim3(NBH, 16), 256, 0, stream>>>(Qb, Kb, VTb, yb);

  // out = y @ out_w^T (BK=64 dbuf, BN=64: 512 blocks -> 2 resident/CU, fp32 out)
  gemm_bt<float, 64><<<dim3(16, 32), 256, 0, stream>>>(yb, woutb, out, 4096, 1024, 1024);
}

// Round 19
// 103.846 us; speedup vs baseline: 1.0663x; 1.0072x over previous
//
#include <hip/hip_runtime.h>
#include <hip/hip_bf16.h>
#include <cstdint>
#include <cstddef>

#define B_SZ   2
#define T_CTX  2048
#define DIM_C  1024
#define NHEAD  16
#define HD     64
#define NBH    (B_SZ*NHEAD)

typedef __attribute__((ext_vector_type(8))) short short8;
typedef __attribute__((ext_vector_type(4))) float f32x4;
typedef __attribute__((ext_vector_type(16))) float f32x16;

union BV8 { short8 s; __hip_bfloat16 h[8]; unsigned short u[8]; };
union U32x4 { uint32_t u[4]; short8 s8; };

#define GLD16(gp, lp) \
  __builtin_amdgcn_global_load_lds((const __attribute__((address_space(1))) void*)(gp), \
                                   (__attribute__((address_space(3))) void*)(lp), 16, 0, 0)

// pack two f32 -> bf16 pair (lo = first arg), pure IR (hazard-safe feed into MFMA)
__device__ inline uint32_t pkbf(float a, float b) {
  union { __hip_bfloat16 h; unsigned short u; } ua, ub;
  ua.h = __float2bfloat16(a);
  ub.h = __float2bfloat16(b);
  return ((uint32_t)ub.u << 16) | (uint32_t)ua.u;
}

// ---------------- fp32 -> bf16 convert, all three inputs in one launch ----------------
__global__ __launch_bounds__(256) void cvt_all(const float* __restrict__ x,
                                               const float* __restrict__ wq,
                                               const float* __restrict__ wo,
                                               __hip_bfloat16* __restrict__ xb,
                                               __hip_bfloat16* __restrict__ wqb,
                                               __hip_bfloat16* __restrict__ wob) {
  int i = blockIdx.x * 256 + threadIdx.x;
  const float* src;
  __hip_bfloat16* dst;
  int off;
  if (i < 1048576) { src = x; dst = xb; off = i; }
  else if (i < 1835008) { src = wq; dst = wqb; off = i - 1048576; }
  else { src = wo; dst = wob; off = i - 1835008; }
  float4 v = reinterpret_cast<const float4*>(src)[off];
  BV8 o;
  o.h[0] = __float2bfloat16(v.x);
  o.h[1] = __float2bfloat16(v.y);
  o.h[2] = __float2bfloat16(v.z);
  o.h[3] = __float2bfloat16(v.w);
  ushort4 st = { o.u[0], o.u[1], o.u[2], o.u[3] };
  reinterpret_cast<ushort4*>(dst)[off] = st;
}

// ---------------- bf16 GEMM, C = A[M,K] * Bt[N,K]^T ----------------
// BK=64, DOUBLE-BUFFERED staging (round-16 proven). BN = 128 (gemm1) or 64
// (gemm2: 48KB LDS -> grid 512 blocks, 2 resident/CU instead of 1).
// 128B LDS rows via pre-swizzled global source (scol ^ ((row&7)<<4)), linear
// global_load_lds dest, same XOR on ds_read_b128. T1 XCD chunking.
template <typename OutT, int BN>
__global__ __launch_bounds__(256) void gemm_bt(const __hip_bfloat16* __restrict__ A,
                                               const __hip_bfloat16* __restrict__ Bt,
                                               OutT* __restrict__ C,
                                               int M, int N, int K) {
  constexpr int NB = BN / 32;               // n-frags per wave (4 or 2)
  constexpr int ABYT = 128 * 128;           // 16KB per buffer
  constexpr int BBYT = BN * 128;            // 16KB or 8KB per buffer
  __shared__ __align__(16) char smem[2 * (ABYT + BBYT)];
  const int tid = threadIdx.x;
  const int w = tid >> 6, l = tid & 63;
  const int l15 = l & 15, l4 = l >> 4;
  const int wr = w >> 1, wc = w & 1;
  // T1: bijective XCD chunking (requires nwg % 8 == 0)
  const int gx = (int)gridDim.x;
  const int nwg = gx * (int)gridDim.y;
  int lin = (int)blockIdx.y * gx + (int)blockIdx.x;
  lin = (lin & 7) * (nwg >> 3) + (lin >> 3);
  const long bm = (long)(lin / gx) * 128;
  const long bn = (long)(lin % gx) * BN;

  f32x4 acc[4][NB] = {};

  const int srow = tid >> 3;            // 0..31 (row within 32-row staging group)
  const int scol = (tid & 7) * 16;      // byte col within 128B row
  const int ssw  = scol ^ ((srow & 7) << 4);  // pre-swizzled source column
  const char* Ab  = (const char*)A;
  const char* Btb = (const char*)Bt;

#define GSTAGE(kt_, buf_)                                                                \
  {                                                                                      \
    char* base_ = smem + (buf_) * (ABYT + BBYT);                                         \
    _Pragma("unroll")                                                                    \
    for (int it = 0; it < 4; ++it) {                                                     \
      long arow = bm + it * 32 + srow;                                                   \
      GLD16(Ab + (arow * K + (kt_)) * 2 + ssw, base_ + it * 4096 + w * 1024);            \
    }                                                                                    \
    _Pragma("unroll")                                                                    \
    for (int it = 0; it < BN / 32; ++it) {                                               \
      long brow = bn + it * 32 + srow;                                                   \
      GLD16(Btb + (brow * K + (kt_)) * 2 + ssw, base_ + ABYT + it * 4096 + w * 1024);    \
    }                                                                                    \
  }

  GSTAGE(0, 0)

  int cur = 0;
  for (int kt = 0; kt < K; kt += 64) {
    __syncthreads();  // buf[cur] staged (vmcnt drained); prior reads of buf^1 done
    if (kt + 64 < K) GSTAGE(kt + 64, cur ^ 1)
    const char* Ac = smem + cur * (ABYT + BBYT);
    const char* Bc = Ac + ABYT;
#pragma unroll
    for (int ksub = 0; ksub < 2; ++ksub) {
      short8 aF[4], bF[NB];
#pragma unroll
      for (int m = 0; m < 4; ++m) {
        int R = wr * 64 + m * 16 + l15;
        aF[m] = *(const short8*)(Ac + R * 128 + ((ksub * 64 + l4 * 16) ^ ((R & 7) << 4)));
      }
#pragma unroll
      for (int n = 0; n < NB; ++n) {
        int R = wc * (BN / 2) + n * 16 + l15;
        bF[n] = *(const short8*)(Bc + R * 128 + ((ksub * 64 + l4 * 16) ^ ((R & 7) << 4)));
      }
#pragma unroll
      for (int m = 0; m < 4; ++m)
#pragma unroll
        for (int n = 0; n < NB; ++n)
          acc[m][n] = __builtin_amdgcn_mfma_f32_16x16x32_bf16(aF[m], bF[n], acc[m][n], 0, 0, 0);
    }
    cur ^= 1;
  }
#undef GSTAGE

#pragma unroll
  for (int m = 0; m < 4; ++m)
#pragma unroll
    for (int n = 0; n < NB; ++n)
#pragma unroll
      for (int r = 0; r < 4; ++r) {
        long row = bm + wr * 64 + m * 16 + l4 * 4 + r;
        long col = bn + wc * (BN / 2) + n * 16 + l15;
        float v = acc[m][n][r];
        if constexpr (sizeof(OutT) == 2) {
          C[row * N + col] = __float2bfloat16(v);
        } else {
          C[row * N + col] = v;
        }
      }
}

// ---------------- RoPE + repack (known-good) ----------------
// Q scale folds softmax 1/8 AND log2(e) so attention softmax can use exp2 natively.
__global__ __launch_bounds__(256) void rope_pack(const __hip_bfloat16* __restrict__ qkv,
                                                 __hip_bfloat16* __restrict__ Qb,
                                                 __hip_bfloat16* __restrict__ Kb,
                                                 __hip_bfloat16* __restrict__ VTb) {
  __shared__ __hip_bfloat16 vt[64][72];
  const int bh = blockIdx.x;
  const int b = bh >> 4, h = bh & 15;
  const int t0 = blockIdx.y * 64;
  const int tid = threadIdx.x;
  const float QSCL = 0.125f * 1.4426950408889634f;

#pragma unroll
  for (int rep = 0; rep < 2; ++rep) {
    int idx = rep * 256 + tid;
    int tt = idx >> 3;
    int d0 = (idx & 7) * 8;
    int t = t0 + tt;
    size_t src = ((size_t)(b * T_CTX + t)) * 3072 + h * 64 + d0;
    BV8 qv, kv, vv, qo, ko;
    qv.s = *(const short8*)(qkv + src);
    kv.s = *(const short8*)(qkv + src + 1024);
    vv.s = *(const short8*)(qkv + src + 2048);
#pragma unroll
    for (int p = 0; p < 4; ++p) {
      int i = (d0 >> 1) + p;
      float inv = exp2f(-13.287712379549449f * ((float)(2 * i) * (1.0f / 64.0f)));
      float ang = (float)t * inv;
      float sn, cn;
      sincosf(ang, &sn, &cn);
      float q1 = __bfloat162float(qv.h[2 * p]);
      float q2 = __bfloat162float(qv.h[2 * p + 1]);
      float k1 = __bfloat162float(kv.h[2 * p]);
      float k2 = __bfloat162float(kv.h[2 * p + 1]);
      qo.h[2 * p]     = __float2bfloat16((q1 * cn - q2 * sn) * QSCL);
      qo.h[2 * p + 1] = __float2bfloat16((q1 * sn + q2 * cn) * QSCL);
      ko.h[2 * p]     = __float2bfloat16(k1 * cn - k2 * sn);
      ko.h[2 * p + 1] = __float2bfloat16(k1 * sn + k2 * cn);
    }
    size_t dst = ((size_t)bh * T_CTX + t) * 64 + d0;
    *(short8*)(Qb + dst) = qo.s;
    *(short8*)(Kb + dst) = ko.s;
#pragma unroll
    for (int j = 0; j < 8; ++j) vt[d0 + j][tt] = vv.h[j];
  }
  __syncthreads();
#pragma unroll
  for (int rep = 0; rep < 2; ++rep) {
    int idx = rep * 256 + tid;
    int d = idx >> 3;
    int toff = (idx & 7) * 8;
    BV8 o;
#pragma unroll
    for (int j = 0; j < 8; ++j) o.h[j] = vt[d][toff + j];
    *(short8*)(VTb + ((size_t)bh * 64 + d) * T_CTX + t0 + toff) = o.s;
  }
}

// ---------------- flash attention (causal), 32x32 MFMA, paired-tile barriers ----------------
// (round-12 structure; change this round: per-tile l-reduce shfl SUNK to the epilogue —
// l is linear, so lane-local accumulation + one hh-merge at the end is exact.)
__global__ __launch_bounds__(256) void flash_attn(const __hip_bfloat16* __restrict__ Qb,
                                                  const __hip_bfloat16* __restrict__ Kb,
                                                  const __hip_bfloat16* __restrict__ VTb,
                                                  __hip_bfloat16* __restrict__ Y) {
  __shared__ __align__(16) char smem[65536];
  const int bh = blockIdx.x;
  const int b = bh >> 4, h = bh & 15;
  const int y = blockIdx.y;
  const int jA = 31 - y;
  const int jB = y;
  const int tid = threadIdx.x;
  const int w = tid >> 6, l = tid & 63;
  const int qsub = w >> 1, kh = w & 1;
  const int l31 = l & 31, hh = l >> 5;
  const int sw7 = (l31 & 7) << 4;
  const int rowb = tid >> 3;
  const int colS = (tid & 7) * 16;

#define STAGE1(gg)                                                                     \
  {                                                                                    \
    const int tt_ = ((gg) <= jA) ? (gg) : (gg) - jA - 1;                               \
    const int kv0_ = tt_ << 6;                                                         \
    char* base_ = smem + (((gg) >> 1) & 1) * 32768 + ((gg) & 1) * 16384;               \
    _Pragma("unroll")                                                                  \
    for (int rnd = 0; rnd < 2; ++rnd) {                                                \
      int row = rnd * 32 + rowb;                                                       \
      int sw = colS ^ ((row & 7) << 4);                                                \
      GLD16((const char*)Kb + (((size_t)bh * T_CTX + kv0_ + row) << 7) + sw,           \
            base_ + rnd * 4096 + w * 1024);                                            \
      GLD16((const char*)VTb + ((((size_t)bh * 64 + row) * T_CTX + kv0_) << 1) + sw,   \
            base_ + 8192 + rnd * 4096 + w * 1024);                                     \
    }                                                                                  \
  }

  f32x16 oA0 = {}, oA1 = {}, oB0 = {}, oB1 = {};
  float lrA = 0.0f, lrB = 0.0f;  // lane-local partial l (hh-merge deferred to epilogue)

  STAGE1(0)
  STAGE1(1)

  int rr = 0;
#pragma unroll
  for (int ph = 0; ph < 2; ++ph) {
    const int j = ph ? jB : jA;
    const int qglob = j * 64 + qsub * 32 + l31;
    f32x16& od0 = ph ? oB0 : oA0;
    f32x16& od1 = ph ? oB1 : oA1;
    float& lrw = ph ? lrB : lrA;

    short8 qB[4];
#pragma unroll
    for (int dblk = 0; dblk < 4; ++dblk)
      qB[dblk] = *(const short8*)(Qb + ((size_t)bh * T_CTX + qglob) * 64 + dblk * 16 + hh * 8);

    for (int t = 0; t <= j; ++t, ++rr) {
      if ((rr & 1) == 0) {
        __syncthreads();
        if (rr + 2 <= 32) STAGE1(rr + 2)
        if (rr + 3 <= 32) STAGE1(rr + 3)
      }
      const char* KsB = smem + ((rr >> 1) & 1) * 32768 + (rr & 1) * 16384;
      const char* VsB = KsB + 8192;
      const int kv0 = t << 6;
      const bool lastT = (t == j);

      if (!(lastT && kh > qsub)) {
        short8 kA[4];
#pragma unroll
        for (int dblk = 0; dblk < 4; ++dblk)
          kA[dblk] = *(const short8*)(KsB + (kh * 32 + l31) * 128 + ((dblk * 32 + hh * 16) ^ sw7));
        short8 vA[2][2];
#pragma unroll
        for (int dt = 0; dt < 2; ++dt)
#pragma unroll
          for (int ks = 0; ks < 2; ++ks)
            vA[dt][ks] = *(const short8*)(VsB + (dt * 32 + l31) * 128 +
                                          ((kh * 64 + ks * 32 + hh * 16) ^ sw7));

        f32x16 sT = {};
#pragma unroll
        for (int dblk = 0; dblk < 4; ++dblk) {
          __builtin_amdgcn_s_setprio(1);
          sT = __builtin_amdgcn_mfma_f32_32x32x16_bf16(kA[dblk], qB[dblk], sT, 0, 0, 0);
          __builtin_amdgcn_s_setprio(0);
        }
        if (lastT && kh == qsub) {
          const int kbase = kv0 + kh * 32 + 4 * hh;
#pragma unroll
          for (int r = 0; r < 16; ++r) {
            int kg = kbase + (r & 3) + 8 * (r >> 2);
            sT[r] = (kg > qglob) ? -1e30f : sT[r];
          }
        }
        float s8[8];
#pragma unroll
        for (int i = 0; i < 8; ++i) {
          sT[i]     = __builtin_amdgcn_exp2f(sT[i]);
          sT[i + 8] = __builtin_amdgcn_exp2f(sT[i + 8]);
          s8[i] = sT[i] + sT[i + 8];
        }
        // lane-local partial only; hh-merge done ONCE at epilogue (l is linear)
        lrw += ((s8[0] + s8[1]) + (s8[2] + s8[3])) + ((s8[4] + s8[5]) + (s8[6] + s8[7]));
        uint32_t wk[8];
#pragma unroll
        for (int i = 0; i < 8; ++i) wk[i] = pkbf(sT[2 * i], sT[2 * i + 1]);
#pragma unroll
        for (int ks = 0; ks < 2; ++ks) {
          const int base = ks * 4;
          uint32_t own0 = wk[base + 0], own1 = wk[base + 1];
          uint32_t own2 = wk[base + 2], own3 = wk[base + 3];
          uint32_t e0 = (uint32_t)__shfl_xor((int)(hh ? own0 : own2), 32);
          uint32_t e1 = (uint32_t)__shfl_xor((int)(hh ? own1 : own3), 32);
          U32x4 u;
          u.u[0] = hh ? e0 : own0;
          u.u[1] = hh ? e1 : own1;
          u.u[2] = hh ? own2 : e0;
          u.u[3] = hh ? own3 : e1;
          __builtin_amdgcn_s_setprio(1);
          od0 = __builtin_amdgcn_mfma_f32_32x32x16_bf16(vA[0][ks], u.s8, od0, 0, 0, 0);
          od1 = __builtin_amdgcn_mfma_f32_32x32x16_bf16(vA[1][ks], u.s8, od1, 0, 0, 0);
          __builtin_amdgcn_s_setprio(0);
        }
      }
    }
  }

  // deferred hh-merge of l partials (exact: addition is associative/commutative)
  lrA += __shfl_xor(lrA, 32);
  lrB += __shfl_xor(lrB, 32);

  __syncthreads();
  {
    float* exch = (float*)smem;
    float* lst = exch + 8192;
    const int slotA = (0 * 2 + qsub) * 2 + kh;
    const int slotB = (1 * 2 + qsub) * 2 + kh;
    const f32x16& nA = kh ? oA0 : oA1;
    const f32x16& nB = kh ? oB0 : oB1;
#pragma unroll
    for (int m = 0; m < 4; ++m) {
      int c = ((2 * m + hh) ^ (l31 & 7)) * 4;
      f32x4 va, vb;
#pragma unroll
      for (int i = 0; i < 4; ++i) { va[i] = nA[m * 4 + i]; vb[i] = nB[m * 4 + i]; }
      *(f32x4*)(exch + slotA * 1024 + l31 * 32 + c) = va;
      *(f32x4*)(exch + slotB * 1024 + l31 * 32 + c) = vb;
    }
    if (hh == 0) {
      lst[slotA * 32 + l31] = lrA;
      lst[slotB * 32 + l31] = lrB;
    }
    __syncthreads();
    const int pA = (0 * 2 + qsub) * 2 + (kh ^ 1);
    const int pB = (1 * 2 + qsub) * 2 + (kh ^ 1);
    float ltA = lrA + lst[pA * 32 + l31];
    float ltB = lrB + lst[pB * 32 + l31];
    f32x16& ownA = kh ? oA1 : oA0;
    f32x16& ownB = kh ? oB1 : oB0;
#pragma unroll
    for (int m = 0; m < 4; ++m) {
      int c = ((2 * m + hh) ^ (l31 & 7)) * 4;
      f32x4 aA = *(const f32x4*)(exch + pA * 1024 + l31 * 32 + c);
      f32x4 aB = *(const f32x4*)(exch + pB * 1024 + l31 * 32 + c);
#pragma unroll
      for (int i = 0; i < 4; ++i) { ownA[m * 4 + i] += aA[i]; ownB[m * 4 + i] += aB[i]; }
    }
#pragma unroll
    for (int sl = 0; sl < 2; ++sl) {
      const f32x16& ov = sl ? ownB : ownA;
      float inv = 1.0f / (sl ? ltB : ltA);
      int q0s = (sl ? jB : jA) * 64 + qsub * 32;
      size_t rowoff = ((size_t)(b * T_CTX + q0s + l31)) * DIM_C + h * 64 + kh * 32;
#pragma unroll
      for (int m = 0; m < 4; ++m) {
        union { ushort4 v; unsigned short us[4]; } st;
#pragma unroll
        for (int i = 0; i < 4; ++i) {
          union { __hip_bfloat16 h2; unsigned short u; } cv;
          cv.h2 = __float2bfloat16(ov[m * 4 + i] * inv);
          st.us[i] = cv.u;
        }
        *(ushort4*)(Y + rowoff + 8 * m + 4 * hh) = st.v;
      }
    }
  }
#undef STAGE1
}

// ---------------- launcher ----------------
extern "C" void kernel_launch(void* const* d_in, const int* in_sizes, int n_in,
                              void* d_out, int out_size, void* d_ws, size_t ws_size,
                              hipStream_t stream) {
  const float* x     = (const float*)d_in[0];
  const float* qkv_w = (const float*)d_in[1];
  const float* out_w = (const float*)d_in[2];
  float* out = (float*)d_out;

  char* ws = (char*)d_ws;
  const size_t MB = 1024 * 1024;
  __hip_bfloat16* xb    = (__hip_bfloat16*)(ws + 0 * MB);
  __hip_bfloat16* wqkvb = (__hip_bfloat16*)(ws + 8 * MB);
  __hip_bfloat16* woutb = (__hip_bfloat16*)(ws + 14 * MB);
  __hip_bfloat16* qkvb  = (__hip_bfloat16*)(ws + 16 * MB);
  __hip_bfloat16* Qb    = (__hip_bfloat16*)(ws + 40 * MB);
  __hip_bfloat16* Kb    = (__hip_bfloat16*)(ws + 48 * MB);
  __hip_bfloat16* VTb   = (__hip_bfloat16*)(ws + 56 * MB);
  __hip_bfloat16* yb    = (__hip_bfloat16*)(ws + 64 * MB);

  // single fused convert launch
  cvt_all<<<8192, 256, 0, stream>>>(x, qkv_w, out_w, xb, wqkvb, woutb);

  // qkv = x @ qkv_w^T (round-16 proven: BK=64 dbuf, BN=128)
  gemm_bt<__hip_bfloat16, 128><<<dim3(24, 32), 256, 0, stream>>>(xb, wqkvb, qkvb, 4096, 3072, 1024);

  rope_pack<<<dim3(32, 32), 256, 0, stream>>>(qkvb, Qb, Kb, VTb);

  // 16 slab-pairs (31-y, y of 64-row slabs) x 32 bh = 512 blocks, 4 waves each
  flash_attn<<<dim3(NBH, 16), 256, 0, stream>>>(Qb, Kb, VTb, yb);

  // out = y @ out_w^T (BK=64 dbuf, BN=64: 512 blocks -> 2 resident/CU, fp32 out)
  gemm_bt<float, 64><<<dim3(16, 32), 256, 0, stream>>>(yb, woutb, out, 4096, 1024, 1024);
}

// Round 20
// 100.987 us; speedup vs baseline: 1.0965x; 1.0283x over previous
//
#include <hip/hip_runtime.h>
#include <hip/hip_bf16.h>
#include <cstdint>
#include <cstddef>

#define B_SZ   2
#define T_CTX  2048
#define DIM_C  1024
#define NHEAD  16
#define HD     64
#define NBH    (B_SZ*NHEAD)

typedef __attribute__((ext_vector_type(8))) short short8;
typedef __attribute__((ext_vector_type(4))) float f32x4;
typedef __attribute__((ext_vector_type(16))) float f32x16;

union BV8 { short8 s; __hip_bfloat16 h[8]; unsigned short u[8]; };
union U32x4 { uint32_t u[4]; short8 s8; };

#define GLD16(gp, lp) \
  __builtin_amdgcn_global_load_lds((const __attribute__((address_space(1))) void*)(gp), \
                                   (__attribute__((address_space(3))) void*)(lp), 16, 0, 0)

// pack two f32 -> bf16 pair (lo = first arg), pure IR (hazard-safe feed into MFMA)
__device__ inline uint32_t pkbf(float a, float b) {
  union { __hip_bfloat16 h; unsigned short u; } ua, ub;
  ua.h = __float2bfloat16(a);
  ub.h = __float2bfloat16(b);
  return ((uint32_t)ub.u << 16) | (uint32_t)ua.u;
}

// ---------------- fp32 -> bf16 convert, all three inputs in one launch ----------------
__global__ __launch_bounds__(256) void cvt_all(const float* __restrict__ x,
                                               const float* __restrict__ wq,
                                               const float* __restrict__ wo,
                                               __hip_bfloat16* __restrict__ xb,
                                               __hip_bfloat16* __restrict__ wqb,
                                               __hip_bfloat16* __restrict__ wob) {
  int i = blockIdx.x * 256 + threadIdx.x;
  const float* src;
  __hip_bfloat16* dst;
  int off;
  if (i < 1048576) { src = x; dst = xb; off = i; }
  else if (i < 1835008) { src = wq; dst = wqb; off = i - 1048576; }
  else { src = wo; dst = wob; off = i - 1835008; }
  float4 v = reinterpret_cast<const float4*>(src)[off];
  BV8 o;
  o.h[0] = __float2bfloat16(v.x);
  o.h[1] = __float2bfloat16(v.y);
  o.h[2] = __float2bfloat16(v.z);
  o.h[3] = __float2bfloat16(v.w);
  ushort4 st = { o.u[0], o.u[1], o.u[2], o.u[3] };
  reinterpret_cast<ushort4*>(dst)[off] = st;
}

// ---------------- bf16 GEMM, C = A[M,K] * Bt[N,K]^T ----------------
// BK=64, DOUBLE-BUFFERED staging. BN = 192 (gemm1: 512 blocks = exactly 2/CU,
// zero tail) or 64 (gemm2). 128B LDS rows via pre-swizzled global source
// (scol ^ ((row&7)<<4)), linear global_load_lds dest, same XOR on ds_read_b128.
// T1 XCD chunking.
template <typename OutT, int BN>
__global__ __launch_bounds__(256) void gemm_bt(const __hip_bfloat16* __restrict__ A,
                                               const __hip_bfloat16* __restrict__ Bt,
                                               OutT* __restrict__ C,
                                               int M, int N, int K) {
  constexpr int NB = BN / 32;               // n-frags per wave (6 or 2)
  constexpr int ABYT = 128 * 128;           // 16KB per buffer
  constexpr int BBYT = BN * 128;            // 24KB or 8KB per buffer
  __shared__ __align__(16) char smem[2 * (ABYT + BBYT)];
  const int tid = threadIdx.x;
  const int w = tid >> 6, l = tid & 63;
  const int l15 = l & 15, l4 = l >> 4;
  const int wr = w >> 1, wc = w & 1;
  // T1: bijective XCD chunking (requires nwg % 8 == 0)
  const int gx = (int)gridDim.x;
  const int nwg = gx * (int)gridDim.y;
  int lin = (int)blockIdx.y * gx + (int)blockIdx.x;
  lin = (lin & 7) * (nwg >> 3) + (lin >> 3);
  const long bm = (long)(lin / gx) * 128;
  const long bn = (long)(lin % gx) * BN;

  f32x4 acc[4][NB] = {};

  const int srow = tid >> 3;            // 0..31 (row within 32-row staging group)
  const int scol = (tid & 7) * 16;      // byte col within 128B row
  const int ssw  = scol ^ ((srow & 7) << 4);  // pre-swizzled source column
  const char* Ab  = (const char*)A;
  const char* Btb = (const char*)Bt;

#define GSTAGE(kt_, buf_)                                                                \
  {                                                                                      \
    char* base_ = smem + (buf_) * (ABYT + BBYT);                                         \
    _Pragma("unroll")                                                                    \
    for (int it = 0; it < 4; ++it) {                                                     \
      long arow = bm + it * 32 + srow;                                                   \
      GLD16(Ab + (arow * K + (kt_)) * 2 + ssw, base_ + it * 4096 + w * 1024);            \
    }                                                                                    \
    _Pragma("unroll")                                                                    \
    for (int it = 0; it < BN / 32; ++it) {                                               \
      long brow = bn + it * 32 + srow;                                                   \
      GLD16(Btb + (brow * K + (kt_)) * 2 + ssw, base_ + ABYT + it * 4096 + w * 1024);    \
    }                                                                                    \
  }

  GSTAGE(0, 0)

  int cur = 0;
  for (int kt = 0; kt < K; kt += 64) {
    __syncthreads();  // buf[cur] staged (vmcnt drained); prior reads of buf^1 done
    if (kt + 64 < K) GSTAGE(kt + 64, cur ^ 1)
    const char* Ac = smem + cur * (ABYT + BBYT);
    const char* Bc = Ac + ABYT;
#pragma unroll
    for (int ksub = 0; ksub < 2; ++ksub) {
      short8 aF[4], bF[NB];
#pragma unroll
      for (int m = 0; m < 4; ++m) {
        int R = wr * 64 + m * 16 + l15;
        aF[m] = *(const short8*)(Ac + R * 128 + ((ksub * 64 + l4 * 16) ^ ((R & 7) << 4)));
      }
#pragma unroll
      for (int n = 0; n < NB; ++n) {
        int R = wc * (BN / 2) + n * 16 + l15;
        bF[n] = *(const short8*)(Bc + R * 128 + ((ksub * 64 + l4 * 16) ^ ((R & 7) << 4)));
      }
#pragma unroll
      for (int m = 0; m < 4; ++m)
#pragma unroll
        for (int n = 0; n < NB; ++n)
          acc[m][n] = __builtin_amdgcn_mfma_f32_16x16x32_bf16(aF[m], bF[n], acc[m][n], 0, 0, 0);
    }
    cur ^= 1;
  }
#undef GSTAGE

#pragma unroll
  for (int m = 0; m < 4; ++m)
#pragma unroll
    for (int n = 0; n < NB; ++n)
#pragma unroll
      for (int r = 0; r < 4; ++r) {
        long row = bm + wr * 64 + m * 16 + l4 * 4 + r;
        long col = bn + wc * (BN / 2) + n * 16 + l15;
        float v = acc[m][n][r];
        if constexpr (sizeof(OutT) == 2) {
          C[row * N + col] = __float2bfloat16(v);
        } else {
          C[row * N + col] = v;
        }
      }
}

// ---------------- RoPE + repack (known-good) ----------------
// Q scale folds softmax 1/8 AND log2(e) so attention softmax can use exp2 natively.
__global__ __launch_bounds__(256) void rope_pack(const __hip_bfloat16* __restrict__ qkv,
                                                 __hip_bfloat16* __restrict__ Qb,
                                                 __hip_bfloat16* __restrict__ Kb,
                                                 __hip_bfloat16* __restrict__ VTb) {
  __shared__ __hip_bfloat16 vt[64][72];
  const int bh = blockIdx.x;
  const int b = bh >> 4, h = bh & 15;
  const int t0 = blockIdx.y * 64;
  const int tid = threadIdx.x;
  const float QSCL = 0.125f * 1.4426950408889634f;

#pragma unroll
  for (int rep = 0; rep < 2; ++rep) {
    int idx = rep * 256 + tid;
    int tt = idx >> 3;
    int d0 = (idx & 7) * 8;
    int t = t0 + tt;
    size_t src = ((size_t)(b * T_CTX + t)) * 3072 + h * 64 + d0;
    BV8 qv, kv, vv, qo, ko;
    qv.s = *(const short8*)(qkv + src);
    kv.s = *(const short8*)(qkv + src + 1024);
    vv.s = *(const short8*)(qkv + src + 2048);
#pragma unroll
    for (int p = 0; p < 4; ++p) {
      int i = (d0 >> 1) + p;
      float inv = exp2f(-13.287712379549449f * ((float)(2 * i) * (1.0f / 64.0f)));
      float ang = (float)t * inv;
      float sn, cn;
      sincosf(ang, &sn, &cn);
      float q1 = __bfloat162float(qv.h[2 * p]);
      float q2 = __bfloat162float(qv.h[2 * p + 1]);
      float k1 = __bfloat162float(kv.h[2 * p]);
      float k2 = __bfloat162float(kv.h[2 * p + 1]);
      qo.h[2 * p]     = __float2bfloat16((q1 * cn - q2 * sn) * QSCL);
      qo.h[2 * p + 1] = __float2bfloat16((q1 * sn + q2 * cn) * QSCL);
      ko.h[2 * p]     = __float2bfloat16(k1 * cn - k2 * sn);
      ko.h[2 * p + 1] = __float2bfloat16(k1 * sn + k2 * cn);
    }
    size_t dst = ((size_t)bh * T_CTX + t) * 64 + d0;
    *(short8*)(Qb + dst) = qo.s;
    *(short8*)(Kb + dst) = ko.s;
#pragma unroll
    for (int j = 0; j < 8; ++j) vt[d0 + j][tt] = vv.h[j];
  }
  __syncthreads();
#pragma unroll
  for (int rep = 0; rep < 2; ++rep) {
    int idx = rep * 256 + tid;
    int d = idx >> 3;
    int toff = (idx & 7) * 8;
    BV8 o;
#pragma unroll
    for (int j = 0; j < 8; ++j) o.h[j] = vt[d][toff + j];
    *(short8*)(VTb + ((size_t)bh * 64 + d) * T_CTX + t0 + toff) = o.s;
  }
}

// ---------------- flash attention (causal), 32x32 MFMA, paired-tile barriers ----------------
// (round-19 known-good: 4 waves = qsub x kh, 64-row balanced slab pairs, k-split,
// fixed-base exp2 softmax, deferred l-merge, end-of-kernel merge, 2 KV tiles/barrier)
__global__ __launch_bounds__(256) void flash_attn(const __hip_bfloat16* __restrict__ Qb,
                                                  const __hip_bfloat16* __restrict__ Kb,
                                                  const __hip_bfloat16* __restrict__ VTb,
                                                  __hip_bfloat16* __restrict__ Y) {
  __shared__ __align__(16) char smem[65536];
  const int bh = blockIdx.x;
  const int b = bh >> 4, h = bh & 15;
  const int y = blockIdx.y;
  const int jA = 31 - y;
  const int jB = y;
  const int tid = threadIdx.x;
  const int w = tid >> 6, l = tid & 63;
  const int qsub = w >> 1, kh = w & 1;
  const int l31 = l & 31, hh = l >> 5;
  const int sw7 = (l31 & 7) << 4;
  const int rowb = tid >> 3;
  const int colS = (tid & 7) * 16;

#define STAGE1(gg)                                                                     \
  {                                                                                    \
    const int tt_ = ((gg) <= jA) ? (gg) : (gg) - jA - 1;                               \
    const int kv0_ = tt_ << 6;                                                         \
    char* base_ = smem + (((gg) >> 1) & 1) * 32768 + ((gg) & 1) * 16384;               \
    _Pragma("unroll")                                                                  \
    for (int rnd = 0; rnd < 2; ++rnd) {                                                \
      int row = rnd * 32 + rowb;                                                       \
      int sw = colS ^ ((row & 7) << 4);                                                \
      GLD16((const char*)Kb + (((size_t)bh * T_CTX + kv0_ + row) << 7) + sw,           \
            base_ + rnd * 4096 + w * 1024);                                            \
      GLD16((const char*)VTb + ((((size_t)bh * 64 + row) * T_CTX + kv0_) << 1) + sw,   \
            base_ + 8192 + rnd * 4096 + w * 1024);                                     \
    }                                                                                  \
  }

  f32x16 oA0 = {}, oA1 = {}, oB0 = {}, oB1 = {};
  float lrA = 0.0f, lrB = 0.0f;  // lane-local partial l (hh-merge deferred to epilogue)

  STAGE1(0)
  STAGE1(1)

  int rr = 0;
#pragma unroll
  for (int ph = 0; ph < 2; ++ph) {
    const int j = ph ? jB : jA;
    const int qglob = j * 64 + qsub * 32 + l31;
    f32x16& od0 = ph ? oB0 : oA0;
    f32x16& od1 = ph ? oB1 : oA1;
    float& lrw = ph ? lrB : lrA;

    short8 qB[4];
#pragma unroll
    for (int dblk = 0; dblk < 4; ++dblk)
      qB[dblk] = *(const short8*)(Qb + ((size_t)bh * T_CTX + qglob) * 64 + dblk * 16 + hh * 8);

    for (int t = 0; t <= j; ++t, ++rr) {
      if ((rr & 1) == 0) {
        __syncthreads();
        if (rr + 2 <= 32) STAGE1(rr + 2)
        if (rr + 3 <= 32) STAGE1(rr + 3)
      }
      const char* KsB = smem + ((rr >> 1) & 1) * 32768 + (rr & 1) * 16384;
      const char* VsB = KsB + 8192;
      const int kv0 = t << 6;
      const bool lastT = (t == j);

      if (!(lastT && kh > qsub)) {
        short8 kA[4];
#pragma unroll
        for (int dblk = 0; dblk < 4; ++dblk)
          kA[dblk] = *(const short8*)(KsB + (kh * 32 + l31) * 128 + ((dblk * 32 + hh * 16) ^ sw7));
        short8 vA[2][2];
#pragma unroll
        for (int dt = 0; dt < 2; ++dt)
#pragma unroll
          for (int ks = 0; ks < 2; ++ks)
            vA[dt][ks] = *(const short8*)(VsB + (dt * 32 + l31) * 128 +
                                          ((kh * 64 + ks * 32 + hh * 16) ^ sw7));

        f32x16 sT = {};
#pragma unroll
        for (int dblk = 0; dblk < 4; ++dblk) {
          __builtin_amdgcn_s_setprio(1);
          sT = __builtin_amdgcn_mfma_f32_32x32x16_bf16(kA[dblk], qB[dblk], sT, 0, 0, 0);
          __builtin_amdgcn_s_setprio(0);
        }
        if (lastT && kh == qsub) {
          const int kbase = kv0 + kh * 32 + 4 * hh;
#pragma unroll
          for (int r = 0; r < 16; ++r) {
            int kg = kbase + (r & 3) + 8 * (r >> 2);
            sT[r] = (kg > qglob) ? -1e30f : sT[r];
          }
        }
        float s8[8];
#pragma unroll
        for (int i = 0; i < 8; ++i) {
          sT[i]     = __builtin_amdgcn_exp2f(sT[i]);
          sT[i + 8] = __builtin_amdgcn_exp2f(sT[i + 8]);
          s8[i] = sT[i] + sT[i + 8];
        }
        // lane-local partial only; hh-merge done ONCE at epilogue (l is linear)
        lrw += ((s8[0] + s8[1]) + (s8[2] + s8[3])) + ((s8[4] + s8[5]) + (s8[6] + s8[7]));
        uint32_t wk[8];
#pragma unroll
        for (int i = 0; i < 8; ++i) wk[i] = pkbf(sT[2 * i], sT[2 * i + 1]);
#pragma unroll
        for (int ks = 0; ks < 2; ++ks) {
          const int base = ks * 4;
          uint32_t own0 = wk[base + 0], own1 = wk[base + 1];
          uint32_t own2 = wk[base + 2], own3 = wk[base + 3];
          uint32_t e0 = (uint32_t)__shfl_xor((int)(hh ? own0 : own2), 32);
          uint32_t e1 = (uint32_t)__shfl_xor((int)(hh ? own1 : own3), 32);
          U32x4 u;
          u.u[0] = hh ? e0 : own0;
          u.u[1] = hh ? e1 : own1;
          u.u[2] = hh ? own2 : e0;
          u.u[3] = hh ? own3 : e1;
          __builtin_amdgcn_s_setprio(1);
          od0 = __builtin_amdgcn_mfma_f32_32x32x16_bf16(vA[0][ks], u.s8, od0, 0, 0, 0);
          od1 = __builtin_amdgcn_mfma_f32_32x32x16_bf16(vA[1][ks], u.s8, od1, 0, 0, 0);
          __builtin_amdgcn_s_setprio(0);
        }
      }
    }
  }

  // deferred hh-merge of l partials (exact: addition is associative/commutative)
  lrA += __shfl_xor(lrA, 32);
  lrB += __shfl_xor(lrB, 32);

  __syncthreads();
  {
    float* exch = (float*)smem;
    float* lst = exch + 8192;
    const int slotA = (0 * 2 + qsub) * 2 + kh;
    const int slotB = (1 * 2 + qsub) * 2 + kh;
    const f32x16& nA = kh ? oA0 : oA1;
    const f32x16& nB = kh ? oB0 : oB1;
#pragma unroll
    for (int m = 0; m < 4; ++m) {
      int c = ((2 * m + hh) ^ (l31 & 7)) * 4;
      f32x4 va, vb;
#pragma unroll
      for (int i = 0; i < 4; ++i) { va[i] = nA[m * 4 + i]; vb[i] = nB[m * 4 + i]; }
      *(f32x4*)(exch + slotA * 1024 + l31 * 32 + c) = va;
      *(f32x4*)(exch + slotB * 1024 + l31 * 32 + c) = vb;
    }
    if (hh == 0) {
      lst[slotA * 32 + l31] = lrA;
      lst[slotB * 32 + l31] = lrB;
    }
    __syncthreads();
    const int pA = (0 * 2 + qsub) * 2 + (kh ^ 1);
    const int pB = (1 * 2 + qsub) * 2 + (kh ^ 1);
    float ltA = lrA + lst[pA * 32 + l31];
    float ltB = lrB + lst[pB * 32 + l31];
    f32x16& ownA = kh ? oA1 : oA0;
    f32x16& ownB = kh ? oB1 : oB0;
#pragma unroll
    for (int m = 0; m < 4; ++m) {
      int c = ((2 * m + hh) ^ (l31 & 7)) * 4;
      f32x4 aA = *(const f32x4*)(exch + pA * 1024 + l31 * 32 + c);
      f32x4 aB = *(const f32x4*)(exch + pB * 1024 + l31 * 32 + c);
#pragma unroll
      for (int i = 0; i < 4; ++i) { ownA[m * 4 + i] += aA[i]; ownB[m * 4 + i] += aB[i]; }
    }
#pragma unroll
    for (int sl = 0; sl < 2; ++sl) {
      const f32x16& ov = sl ? ownB : ownA;
      float inv = 1.0f / (sl ? ltB : ltA);
      int q0s = (sl ? jB : jA) * 64 + qsub * 32;
      size_t rowoff = ((size_t)(b * T_CTX + q0s + l31)) * DIM_C + h * 64 + kh * 32;
#pragma unroll
      for (int m = 0; m < 4; ++m) {
        union { ushort4 v; unsigned short us[4]; } st;
#pragma unroll
        for (int i = 0; i < 4; ++i) {
          union { __hip_bfloat16 h2; unsigned short u; } cv;
          cv.h2 = __float2bfloat16(ov[m * 4 + i] * inv);
          st.us[i] = cv.u;
        }
        *(ushort4*)(Y + rowoff + 8 * m + 4 * hh) = st.v;
      }
    }
  }
#undef STAGE1
}

// ---------------- launcher ----------------
extern "C" void kernel_launch(void* const* d_in, const int* in_sizes, int n_in,
                              void* d_out, int out_size, void* d_ws, size_t ws_size,
                              hipStream_t stream) {
  const float* x     = (const float*)d_in[0];
  const float* qkv_w = (const float*)d_in[1];
  const float* out_w = (const float*)d_in[2];
  float* out = (float*)d_out;

  char* ws = (char*)d_ws;
  const size_t MB = 1024 * 1024;
  __hip_bfloat16* xb    = (__hip_bfloat16*)(ws + 0 * MB);
  __hip_bfloat16* wqkvb = (__hip_bfloat16*)(ws + 8 * MB);
  __hip_bfloat16* woutb = (__hip_bfloat16*)(ws + 14 * MB);
  __hip_bfloat16* qkvb  = (__hip_bfloat16*)(ws + 16 * MB);
  __hip_bfloat16* Qb    = (__hip_bfloat16*)(ws + 40 * MB);
  __hip_bfloat16* Kb    = (__hip_bfloat16*)(ws + 48 * MB);
  __hip_bfloat16* VTb   = (__hip_bfloat16*)(ws + 56 * MB);
  __hip_bfloat16* yb    = (__hip_bfloat16*)(ws + 64 * MB);

  // single fused convert launch
  cvt_all<<<8192, 256, 0, stream>>>(x, qkv_w, out_w, xb, wqkvb, woutb);

  // qkv = x @ qkv_w^T (BK=64 dbuf, BN=192: 512 blocks = exactly 2/CU, zero tail)
  gemm_bt<__hip_bfloat16, 192><<<dim3(16, 32), 256, 0, stream>>>(xb, wqkvb, qkvb, 4096, 3072, 1024);

  rope_pack<<<dim3(32, 32), 256, 0, stream>>>(qkvb, Qb, Kb, VTb);

  // 16 slab-pairs (31-y, y of 64-row slabs) x 32 bh = 512 blocks, 4 waves each
  flash_attn<<<dim3(NBH, 16), 256, 0, stream>>>(Qb, Kb, VTb, yb);

  // out = y @ out_w^T (BK=64 dbuf, BN=64: 512 blocks -> 2 resident/CU, fp32 out)
  gemm_bt<float, 64><<<dim3(16, 32), 256, 0, stream>>>(yb, woutb, out, 4096, 1024, 1024);
}

// Round 21
// 96.422 us; speedup vs baseline: 1.1484x; 1.0473x over previous
//
#include <hip/hip_runtime.h>
#include <hip/hip_bf16.h>
#include <cstdint>
#include <cstddef>

#define B_SZ   2
#define T_CTX  2048
#define DIM_C  1024
#define NHEAD  16
#define HD     64
#define NBH    (B_SZ*NHEAD)

typedef __attribute__((ext_vector_type(8))) short short8;
typedef __attribute__((ext_vector_type(4))) float f32x4;
typedef __attribute__((ext_vector_type(16))) float f32x16;

union BV8 { short8 s; __hip_bfloat16 h[8]; unsigned short u[8]; };
union U32x4 { uint32_t u[4]; short8 s8; };

#define GLD16(gp, lp) \
  __builtin_amdgcn_global_load_lds((const __attribute__((address_space(1))) void*)(gp), \
                                   (__attribute__((address_space(3))) void*)(lp), 16, 0, 0)

// pack two f32 -> bf16 pair (lo = first arg), pure IR (hazard-safe feed into MFMA)
__device__ inline uint32_t pkbf(float a, float b) {
  union { __hip_bfloat16 h; unsigned short u; } ua, ub;
  ua.h = __float2bfloat16(a);
  ub.h = __float2bfloat16(b);
  return ((uint32_t)ub.u << 16) | (uint32_t)ua.u;
}

// ---------------- fp32 -> bf16 convert, all three inputs in one launch ----------------
__global__ __launch_bounds__(256) void cvt_all(const float* __restrict__ x,
                                               const float* __restrict__ wq,
                                               const float* __restrict__ wo,
                                               __hip_bfloat16* __restrict__ xb,
                                               __hip_bfloat16* __restrict__ wqb,
                                               __hip_bfloat16* __restrict__ wob) {
  int i = blockIdx.x * 256 + threadIdx.x;
  const float* src;
  __hip_bfloat16* dst;
  int off;
  if (i < 1048576) { src = x; dst = xb; off = i; }
  else if (i < 1835008) { src = wq; dst = wqb; off = i - 1048576; }
  else { src = wo; dst = wob; off = i - 1835008; }
  float4 v = reinterpret_cast<const float4*>(src)[off];
  BV8 o;
  o.h[0] = __float2bfloat16(v.x);
  o.h[1] = __float2bfloat16(v.y);
  o.h[2] = __float2bfloat16(v.z);
  o.h[3] = __float2bfloat16(v.w);
  ushort4 st = { o.u[0], o.u[1], o.u[2], o.u[3] };
  reinterpret_cast<ushort4*>(dst)[off] = st;
}

// ---------------- bf16 GEMM, C = A[M,K] * Bt[N,K]^T ----------------
// BK=64, DOUBLE-BUFFERED staging. BN = 192 (gemm1: 512 blocks = exactly 2/CU,
// zero tail) or 64 (gemm2). 128B LDS rows via pre-swizzled global source
// (scol ^ ((row&7)<<4)), linear global_load_lds dest, same XOR on ds_read_b128.
// T1 XCD chunking.
template <typename OutT, int BN>
__global__ __launch_bounds__(256) void gemm_bt(const __hip_bfloat16* __restrict__ A,
                                               const __hip_bfloat16* __restrict__ Bt,
                                               OutT* __restrict__ C,
                                               int M, int N, int K) {
  constexpr int NB = BN / 32;               // n-frags per wave (6 or 2)
  constexpr int ABYT = 128 * 128;           // 16KB per buffer
  constexpr int BBYT = BN * 128;            // 24KB or 8KB per buffer
  __shared__ __align__(16) char smem[2 * (ABYT + BBYT)];
  const int tid = threadIdx.x;
  const int w = tid >> 6, l = tid & 63;
  const int l15 = l & 15, l4 = l >> 4;
  const int wr = w >> 1, wc = w & 1;
  // T1: bijective XCD chunking (requires nwg % 8 == 0)
  const int gx = (int)gridDim.x;
  const int nwg = gx * (int)gridDim.y;
  int lin = (int)blockIdx.y * gx + (int)blockIdx.x;
  lin = (lin & 7) * (nwg >> 3) + (lin >> 3);
  const long bm = (long)(lin / gx) * 128;
  const long bn = (long)(lin % gx) * BN;

  f32x4 acc[4][NB] = {};

  const int srow = tid >> 3;            // 0..31 (row within 32-row staging group)
  const int scol = (tid & 7) * 16;      // byte col within 128B row
  const int ssw  = scol ^ ((srow & 7) << 4);  // pre-swizzled source column
  const char* Ab  = (const char*)A;
  const char* Btb = (const char*)Bt;

#define GSTAGE(kt_, buf_)                                                                \
  {                                                                                      \
    char* base_ = smem + (buf_) * (ABYT + BBYT);                                         \
    _Pragma("unroll")                                                                    \
    for (int it = 0; it < 4; ++it) {                                                     \
      long arow = bm + it * 32 + srow;                                                   \
      GLD16(Ab + (arow * K + (kt_)) * 2 + ssw, base_ + it * 4096 + w * 1024);            \
    }                                                                                    \
    _Pragma("unroll")                                                                    \
    for (int it = 0; it < BN / 32; ++it) {                                               \
      long brow = bn + it * 32 + srow;                                                   \
      GLD16(Btb + (brow * K + (kt_)) * 2 + ssw, base_ + ABYT + it * 4096 + w * 1024);    \
    }                                                                                    \
  }

  GSTAGE(0, 0)

  int cur = 0;
  for (int kt = 0; kt < K; kt += 64) {
    __syncthreads();  // buf[cur] staged (vmcnt drained); prior reads of buf^1 done
    if (kt + 64 < K) GSTAGE(kt + 64, cur ^ 1)
    const char* Ac = smem + cur * (ABYT + BBYT);
    const char* Bc = Ac + ABYT;
#pragma unroll
    for (int ksub = 0; ksub < 2; ++ksub) {
      short8 aF[4], bF[NB];
#pragma unroll
      for (int m = 0; m < 4; ++m) {
        int R = wr * 64 + m * 16 + l15;
        aF[m] = *(const short8*)(Ac + R * 128 + ((ksub * 64 + l4 * 16) ^ ((R & 7) << 4)));
      }
#pragma unroll
      for (int n = 0; n < NB; ++n) {
        int R = wc * (BN / 2) + n * 16 + l15;
        bF[n] = *(const short8*)(Bc + R * 128 + ((ksub * 64 + l4 * 16) ^ ((R & 7) << 4)));
      }
#pragma unroll
      for (int m = 0; m < 4; ++m)
#pragma unroll
        for (int n = 0; n < NB; ++n)
          acc[m][n] = __builtin_amdgcn_mfma_f32_16x16x32_bf16(aF[m], bF[n], acc[m][n], 0, 0, 0);
    }
    cur ^= 1;
  }
#undef GSTAGE

#pragma unroll
  for (int m = 0; m < 4; ++m)
#pragma unroll
    for (int n = 0; n < NB; ++n)
#pragma unroll
      for (int r = 0; r < 4; ++r) {
        long row = bm + wr * 64 + m * 16 + l4 * 4 + r;
        long col = bn + wc * (BN / 2) + n * 16 + l15;
        float v = acc[m][n][r];
        if constexpr (sizeof(OutT) == 2) {
          C[row * N + col] = __float2bfloat16(v);
        } else {
          C[row * N + col] = v;
        }
      }
}

// ---------------- RoPE + repack (known-good) ----------------
// Q scale folds softmax 1/8 AND log2(e) so attention softmax can use exp2 natively.
__global__ __launch_bounds__(256) void rope_pack(const __hip_bfloat16* __restrict__ qkv,
                                                 __hip_bfloat16* __restrict__ Qb,
                                                 __hip_bfloat16* __restrict__ Kb,
                                                 __hip_bfloat16* __restrict__ VTb) {
  __shared__ __hip_bfloat16 vt[64][72];
  const int bh = blockIdx.x;
  const int b = bh >> 4, h = bh & 15;
  const int t0 = blockIdx.y * 64;
  const int tid = threadIdx.x;
  const float QSCL = 0.125f * 1.4426950408889634f;

#pragma unroll
  for (int rep = 0; rep < 2; ++rep) {
    int idx = rep * 256 + tid;
    int tt = idx >> 3;
    int d0 = (idx & 7) * 8;
    int t = t0 + tt;
    size_t src = ((size_t)(b * T_CTX + t)) * 3072 + h * 64 + d0;
    BV8 qv, kv, vv, qo, ko;
    qv.s = *(const short8*)(qkv + src);
    kv.s = *(const short8*)(qkv + src + 1024);
    vv.s = *(const short8*)(qkv + src + 2048);
#pragma unroll
    for (int p = 0; p < 4; ++p) {
      int i = (d0 >> 1) + p;
      float inv = exp2f(-13.287712379549449f * ((float)(2 * i) * (1.0f / 64.0f)));
      float ang = (float)t * inv;
      float sn, cn;
      sincosf(ang, &sn, &cn);
      float q1 = __bfloat162float(qv.h[2 * p]);
      float q2 = __bfloat162float(qv.h[2 * p + 1]);
      float k1 = __bfloat162float(kv.h[2 * p]);
      float k2 = __bfloat162float(kv.h[2 * p + 1]);
      qo.h[2 * p]     = __float2bfloat16((q1 * cn - q2 * sn) * QSCL);
      qo.h[2 * p + 1] = __float2bfloat16((q1 * sn + q2 * cn) * QSCL);
      ko.h[2 * p]     = __float2bfloat16(k1 * cn - k2 * sn);
      ko.h[2 * p + 1] = __float2bfloat16(k1 * sn + k2 * cn);
    }
    size_t dst = ((size_t)bh * T_CTX + t) * 64 + d0;
    *(short8*)(Qb + dst) = qo.s;
    *(short8*)(Kb + dst) = ko.s;
#pragma unroll
    for (int j = 0; j < 8; ++j) vt[d0 + j][tt] = vv.h[j];
  }
  __syncthreads();
#pragma unroll
  for (int rep = 0; rep < 2; ++rep) {
    int idx = rep * 256 + tid;
    int d = idx >> 3;
    int toff = (idx & 7) * 8;
    BV8 o;
#pragma unroll
    for (int j = 0; j < 8; ++j) o.h[j] = vt[d][toff + j];
    *(short8*)(VTb + ((size_t)bh * 64 + d) * T_CTX + t0 + toff) = o.s;
  }
}

// ---------------- flash attention (causal), 32x32 MFMA, 8-wave 128-row slabs ----------------
// 16 slabs of 128 q-rows; block y runs slab 15-y then slab y: exactly 34 KV tiles.
// 8 waves = (qsub 0..3, kh 0..1): each wave 32q x 32k per tile -> staged tile amortized
// over 2x the q-rows of the 4-wave version (halved per-CU staging / LDS-fill traffic).
// Same paired-tile barrier skeleton (barrier every even rr, 4 x 16KB tile slots).
// General causal conditions: skip iff kv0+kh*32 > Q0+31; mask iff kv0+kh*32+31 > Q0.
// Fixed-base exp2 softmax, lane-local l (deferred merges), end-of-kernel 16-slot merge.
__global__ __launch_bounds__(512) void flash_attn(const __hip_bfloat16* __restrict__ Qb,
                                                  const __hip_bfloat16* __restrict__ Kb,
                                                  const __hip_bfloat16* __restrict__ VTb,
                                                  __hip_bfloat16* __restrict__ Y) {
  __shared__ __align__(16) char smem[67584];  // 4 x 16KB staging slots; merge reuses 66KB
  const int bh = blockIdx.x;
  const int b = bh >> 4, h = bh & 15;
  const int y = blockIdx.y;          // 0..7
  const int jA = 15 - y;             // slab A (128 q-rows at jA*128)
  const int jB = y;                  // slab B
  const int tmaxA = 2 * jA + 1;      // tiles-1 for slab A (KVBLK=64)
  const int tmaxB = 2 * jB + 1;      // total tiles = (tmaxA+1)+(tmaxB+1) = 34
  const int tid = threadIdx.x;
  const int w = tid >> 6, l = tid & 63;   // w 0..7
  const int qsub = w >> 1, kh = w & 1;
  const int l31 = l & 31, hh = l >> 5;
  const int sw7 = (l31 & 7) << 4;
  const int rowb = w * 8 + (l >> 3);      // 0..63 (staging row; one GLD16 per thread per tensor)
  const int colS = (l & 7) * 16;

#define STAGE1(gg)                                                                     \
  {                                                                                    \
    const int tt_ = ((gg) <= tmaxA) ? (gg) : (gg) - tmaxA - 1;                         \
    const int kv0_ = tt_ << 6;                                                         \
    char* base_ = smem + (((gg) >> 1) & 1) * 32768 + ((gg) & 1) * 16384;               \
    int sw = colS ^ ((rowb & 7) << 4);                                                 \
    GLD16((const char*)Kb + (((size_t)bh * T_CTX + kv0_ + rowb) << 7) + sw,            \
          base_ + w * 1024);                                                           \
    GLD16((const char*)VTb + ((((size_t)bh * 64 + rowb) * T_CTX + kv0_) << 1) + sw,    \
          base_ + 8192 + w * 1024);                                                    \
  }

  f32x16 oA0 = {}, oA1 = {}, oB0 = {}, oB1 = {};
  float lrA = 0.0f, lrB = 0.0f;  // lane-local partial l (hh-merge deferred to epilogue)

  STAGE1(0)
  STAGE1(1)

  int rr = 0;  // global round counter 0..33
#pragma unroll
  for (int ph = 0; ph < 2; ++ph) {
    const int slab = ph ? jB : jA;
    const int tmax = ph ? tmaxB : tmaxA;
    const int Q0 = slab * 128 + qsub * 32;
    const int qglob = Q0 + l31;
    f32x16& od0 = ph ? oB0 : oA0;
    f32x16& od1 = ph ? oB1 : oA1;
    float& lrw = ph ? lrB : lrA;

    short8 qB[4];
#pragma unroll
    for (int dblk = 0; dblk < 4; ++dblk)
      qB[dblk] = *(const short8*)(Qb + ((size_t)bh * T_CTX + qglob) * 64 + dblk * 16 + hh * 8);

    for (int t = 0; t <= tmax; ++t, ++rr) {
      if ((rr & 1) == 0) {
        __syncthreads();  // tiles rr, rr+1 staged; prior reads of other buffer done
        if (rr + 2 <= 33) STAGE1(rr + 2)
        if (rr + 3 <= 33) STAGE1(rr + 3)
      }
      const char* KsB = smem + ((rr >> 1) & 1) * 32768 + (rr & 1) * 16384;
      const char* VsB = KsB + 8192;
      const int kv0 = t << 6;
      const int kbase0 = kv0 + kh * 32;  // wave's k-half start

      if (kbase0 <= Q0 + 31) {  // not fully masked (wave-uniform; barriers unaffected)
        short8 kA[4];
#pragma unroll
        for (int dblk = 0; dblk < 4; ++dblk)
          kA[dblk] = *(const short8*)(KsB + (kh * 32 + l31) * 128 + ((dblk * 32 + hh * 16) ^ sw7));
        short8 vA[2][2];
#pragma unroll
        for (int dt = 0; dt < 2; ++dt)
#pragma unroll
          for (int ks = 0; ks < 2; ++ks)
            vA[dt][ks] = *(const short8*)(VsB + (dt * 32 + l31) * 128 +
                                          ((kh * 64 + ks * 32 + hh * 16) ^ sw7));

        f32x16 sT = {};
#pragma unroll
        for (int dblk = 0; dblk < 4; ++dblk) {
          __builtin_amdgcn_s_setprio(1);
          sT = __builtin_amdgcn_mfma_f32_32x32x16_bf16(kA[dblk], qB[dblk], sT, 0, 0, 0);
          __builtin_amdgcn_s_setprio(0);
        }
        if (kbase0 + 31 > Q0) {  // diagonal 32x32 block: causal mask
          const int kbase = kbase0 + 4 * hh;
#pragma unroll
          for (int r = 0; r < 16; ++r) {
            int kg = kbase + (r & 3) + 8 * (r >> 2);
            sT[r] = (kg > qglob) ? -1e30f : sT[r];
          }
        }
        float s8[8];
#pragma unroll
        for (int i = 0; i < 8; ++i) {
          sT[i]     = __builtin_amdgcn_exp2f(sT[i]);
          sT[i + 8] = __builtin_amdgcn_exp2f(sT[i + 8]);
          s8[i] = sT[i] + sT[i + 8];
        }
        // lane-local partial only; hh-merge done ONCE at epilogue (l is linear)
        lrw += ((s8[0] + s8[1]) + (s8[2] + s8[3])) + ((s8[4] + s8[5]) + (s8[6] + s8[7]));
        uint32_t wk[8];
#pragma unroll
        for (int i = 0; i < 8; ++i) wk[i] = pkbf(sT[2 * i], sT[2 * i + 1]);
#pragma unroll
        for (int ks = 0; ks < 2; ++ks) {
          const int base = ks * 4;
          uint32_t own0 = wk[base + 0], own1 = wk[base + 1];
          uint32_t own2 = wk[base + 2], own3 = wk[base + 3];
          uint32_t e0 = (uint32_t)__shfl_xor((int)(hh ? own0 : own2), 32);
          uint32_t e1 = (uint32_t)__shfl_xor((int)(hh ? own1 : own3), 32);
          U32x4 u;
          u.u[0] = hh ? e0 : own0;
          u.u[1] = hh ? e1 : own1;
          u.u[2] = hh ? own2 : e0;
          u.u[3] = hh ? own3 : e1;
          __builtin_amdgcn_s_setprio(1);
          od0 = __builtin_amdgcn_mfma_f32_32x32x16_bf16(vA[0][ks], u.s8, od0, 0, 0, 0);
          od1 = __builtin_amdgcn_mfma_f32_32x32x16_bf16(vA[1][ks], u.s8, od1, 0, 0, 0);
          __builtin_amdgcn_s_setprio(0);
        }
      }
    }
  }

  // deferred hh-merge of l partials (exact: addition is associative/commutative)
  lrA += __shfl_xor(lrA, 32);
  lrB += __shfl_xor(lrB, 32);

  __syncthreads();  // all staging + LDS reads done; smem free for exchange
  {
    float* exch = (float*)smem;   // 16 slots x 1024 f32 (32q x 32d, XOR-swizzled chunks)
    float* lst = exch + 16384;    // l partials: [16 slots][32] at byte 65536
    const int slotA = (0 * 4 + qsub) * 2 + kh;
    const int slotB = (1 * 4 + qsub) * 2 + kh;
    const f32x16& nA = kh ? oA0 : oA1;  // non-owned dt = 1-kh
    const f32x16& nB = kh ? oB0 : oB1;
#pragma unroll
    for (int m = 0; m < 4; ++m) {
      int c = ((2 * m + hh) ^ (l31 & 7)) * 4;
      f32x4 va, vb;
#pragma unroll
      for (int i = 0; i < 4; ++i) { va[i] = nA[m * 4 + i]; vb[i] = nB[m * 4 + i]; }
      *(f32x4*)(exch + slotA * 1024 + l31 * 32 + c) = va;
      *(f32x4*)(exch + slotB * 1024 + l31 * 32 + c) = vb;
    }
    if (hh == 0) {
      lst[slotA * 32 + l31] = lrA;
      lst[slotB * 32 + l31] = lrB;
    }
    __syncthreads();
    const int pA = (0 * 4 + qsub) * 2 + (kh ^ 1);
    const int pB = (1 * 4 + qsub) * 2 + (kh ^ 1);
    float ltA = lrA + lst[pA * 32 + l31];
    float ltB = lrB + lst[pB * 32 + l31];
    f32x16& ownA = kh ? oA1 : oA0;
    f32x16& ownB = kh ? oB1 : oB0;
#pragma unroll
    for (int m = 0; m < 4; ++m) {
      int c = ((2 * m + hh) ^ (l31 & 7)) * 4;
      f32x4 aA = *(const f32x4*)(exch + pA * 1024 + l31 * 32 + c);
      f32x4 aB = *(const f32x4*)(exch + pB * 1024 + l31 * 32 + c);
#pragma unroll
      for (int i = 0; i < 4; ++i) { ownA[m * 4 + i] += aA[i]; ownB[m * 4 + i] += aB[i]; }
    }
    // write Y: wave's owned 32 d-cols (kh half), both slabs
#pragma unroll
    for (int sl = 0; sl < 2; ++sl) {
      const f32x16& ov = sl ? ownB : ownA;
      float inv = 1.0f / (sl ? ltB : ltA);
      int q0s = (sl ? jB : jA) * 128 + qsub * 32;
      size_t rowoff = ((size_t)(b * T_CTX + q0s + l31)) * DIM_C + h * 64 + kh * 32;
#pragma unroll
      for (int m = 0; m < 4; ++m) {
        union { ushort4 v; unsigned short us[4]; } st;
#pragma unroll
        for (int i = 0; i < 4; ++i) {
          union { __hip_bfloat16 h2; unsigned short u; } cv;
          cv.h2 = __float2bfloat16(ov[m * 4 + i] * inv);
          st.us[i] = cv.u;
        }
        *(ushort4*)(Y + rowoff + 8 * m + 4 * hh) = st.v;
      }
    }
  }
#undef STAGE1
}

// ---------------- launcher ----------------
extern "C" void kernel_launch(void* const* d_in, const int* in_sizes, int n_in,
                              void* d_out, int out_size, void* d_ws, size_t ws_size,
                              hipStream_t stream) {
  const float* x     = (const float*)d_in[0];
  const float* qkv_w = (const float*)d_in[1];
  const float* out_w = (const float*)d_in[2];
  float* out = (float*)d_out;

  char* ws = (char*)d_ws;
  const size_t MB = 1024 * 1024;
  __hip_bfloat16* xb    = (__hip_bfloat16*)(ws + 0 * MB);
  __hip_bfloat16* wqkvb = (__hip_bfloat16*)(ws + 8 * MB);
  __hip_bfloat16* woutb = (__hip_bfloat16*)(ws + 14 * MB);
  __hip_bfloat16* qkvb  = (__hip_bfloat16*)(ws + 16 * MB);
  __hip_bfloat16* Qb    = (__hip_bfloat16*)(ws + 40 * MB);
  __hip_bfloat16* Kb    = (__hip_bfloat16*)(ws + 48 * MB);
  __hip_bfloat16* VTb   = (__hip_bfloat16*)(ws + 56 * MB);
  __hip_bfloat16* yb    = (__hip_bfloat16*)(ws + 64 * MB);

  // single fused convert launch
  cvt_all<<<8192, 256, 0, stream>>>(x, qkv_w, out_w, xb, wqkvb, woutb);

  // qkv = x @ qkv_w^T (BK=64 dbuf, BN=192: 512 blocks = exactly 2/CU, zero tail)
  gemm_bt<__hip_bfloat16, 192><<<dim3(16, 32), 256, 0, stream>>>(xb, wqkvb, qkvb, 4096, 3072, 1024);

  rope_pack<<<dim3(32, 32), 256, 0, stream>>>(qkvb, Qb, Kb, VTb);

  // 8 slab-pairs (15-y, y of 128-row slabs) x 32 bh = 256 blocks, 8 waves each
  flash_attn<<<dim3(NBH, 8), 512, 0, stream>>>(Qb, Kb, VTb, yb);

  // out = y @ out_w^T (BK=64 dbuf, BN=64: 512 blocks -> 2 resident/CU, fp32 out)
  gemm_bt<float, 64><<<dim3(16, 32), 256, 0, stream>>>(yb, woutb, out, 4096, 1024, 1024);
}